// Round 14
// baseline (594.921 us; speedup 1.0000x reference)
//
#include <hip/hip_runtime.h>
#include <math.h>

#ifndef M_PI
#define M_PI 3.14159265358979323846
#endif

#define BB 4
#define TT 500
#define NSAMP 120000
#define NHARM 32
#define NFFT 256
#define NBIN 129
#define NHOPF 64
#define NFRAMES 1876
#define HID 64
#define MLPD 128
#define FEATD 88

#define R_MAG ((float)(500.0/1876.0))
#define R_UP_F ((float)(500.0/120000.0))

// ---- workspace layout (float offsets) ----
#define OFF_HARML 0
#define OFF_HARMR 64000
#define OFF_AMP   128000
#define OFF_NMAGL 130000
#define OFF_NMAGR 388000
#define OFF_C1    646000
#define OFF_H1    646128
#define OFF_GI    (OFF_H1+256000)
#define OFF_GOUT  (OFF_GI+384000)
#define OFF_SPECL (OFF_GOUT+128000)
#define OFF_SPECR (OFF_SPECL+4*NFRAMES*258)
/* end = 5286160 floats = 21.1 MB */

// f32 upsample position/interp chain, bit-exact to numpy float32 elementwise
__device__ __forceinline__ void up_coords(int m, int* i0, int* i1, float* w, float* w1){
  float pos = __fadd_rn(__fmul_rn(__fadd_rn((float)m, 0.5f), R_UP_F), -0.5f);
  pos = fminf(fmaxf(pos, 0.0f), 499.0f);
  int a = (int)pos;
  *i0 = a; *i1 = min(a+1, TT-1);
  float ww = __fsub_rn(pos, (float)a);
  *w = ww; *w1 = __fsub_rn(1.0f, ww);
}
__device__ __forceinline__ float f0_up_elem(const float* __restrict__ f0s, int m){
  int i0,i1; float w,w1;
  up_coords(m,&i0,&i1,&w,&w1);
  return __fadd_rn(__fmul_rn(f0s[i0], w1), __fmul_rn(f0s[i1], w));
}

// ---------------- fused encoding + pre1 matmul ----------------
__global__ __launch_bounds__(128) void k_encmm(const float* __restrict__ f0,
    const float* __restrict__ ldb, const float* __restrict__ vel,
    const float* __restrict__ Wp1, const float* __restrict__ bp1,
    float* __restrict__ h1){
  int row = blockIdx.x;
  int b = row / TT;
  int tid = threadIdx.x;
  __shared__ float feat[FEATD];
  if (tid < FEATD){
    float f = f0[row];
    float gate = (f > 0.0f) ? 1.0f : 0.0f;
    float fs = fmaxf(f, 20.0f);
    float fn = (logf(fs) - (float)2.995732273553991) / (float)5.5214609178622464;
    fn = fminf(fmaxf(fn, 0.0f), 1.0f);
    float ln = fminf(fmaxf((ldb[row] + 80.0f) / 80.0f, 0.0f), 1.0f);
    float vn = fminf(fmaxf(vel[b] / 7.0f, 0.0f), 1.0f);
    float norm; int i; float g2 = 1.0f;
    if (tid < 64){ i = (tid>>1) + 1; norm = fn; g2 = gate; }
    else if (tid < 80){ i = ((tid-64)>>1) + 1; norm = ln; }
    else { i = ((tid-80)>>1) + 1; norm = vn; }
    float ang = (float)M_PI * (float)i * norm;
    feat[tid] = ((tid & 1) ? cosf(ang) : sinf(ang)) * g2;
  }
  __syncthreads();
  const float* wp = Wp1 + tid*FEATD;
  float acc = bp1[tid];
  #pragma unroll 8
  for (int i=0;i<FEATD;i++) acc = fmaf(feat[i], wp[i], acc);
  h1[(size_t)row*MLPD + tid] = fmaxf(acc, 0.0f);
}

// ---------------- fused pre2 matmul + gi matmul ----------------
__global__ __launch_bounds__(192) void k_mm2gi(const float* __restrict__ h1,
    const float* __restrict__ Wp2, const float* __restrict__ bp2,
    const float* __restrict__ Wih, const float* __restrict__ bih,
    float* __restrict__ gi){
  int row = blockIdx.x;
  int tid = threadIdx.x;
  __shared__ float h1s[MLPD];
  __shared__ float h2s[MLPD];
  if (tid < MLPD) h1s[tid] = h1[(size_t)row*MLPD + tid];
  __syncthreads();
  if (tid < MLPD){
    const float* wp = Wp2 + tid*MLPD;
    float acc = bp2[tid];
    #pragma unroll 8
    for (int i=0;i<MLPD;i++) acc = fmaf(h1s[i], wp[i], acc);
    h2s[tid] = fmaxf(acc, 0.0f);
  }
  __syncthreads();
  const float* wp = Wih + tid*MLPD;
  float acc = bih[tid];
  #pragma unroll 8
  for (int i=0;i<MLPD;i++) acc = fmaf(h2s[i], wp[i], acc);
  gi[(size_t)row*192 + tid] = acc;
}

// numpy-exact pairwise block sum (leaf of the depth-10 perfect tree)
__device__ float np_block_sum(const float* __restrict__ f0s, int off, int n, float kf){
  float r[8];
  #pragma unroll
  for (int j=0;j<8;j++) r[j] = __fmul_rn(f0_up_elem(f0s, off+j), kf);
  int lim = n - (n & 7);
  int i = 8;
  for (; i<lim; i+=8){
    #pragma unroll
    for (int j=0;j<8;j++)
      r[j] = __fadd_rn(r[j], __fmul_rn(f0_up_elem(f0s, off+i+j), kf));
  }
  float res = __fadd_rn(__fadd_rn(__fadd_rn(r[0],r[1]), __fadd_rn(r[2],r[3])),
                        __fadd_rn(__fadd_rn(r[4],r[5]), __fadd_rn(r[6],r[7])));
  for (; i<n; i++)
    res = __fadd_rn(res, __fmul_rn(f0_up_elem(f0s, off+i), kf));
  return res;
}

// ---------------- fused mid: GRU + STFT + meanf0 ----------------
#define MID_GRU   BB
#define MID_MF    (MID_GRU + BB*32)
#define STFT_JOBS (2*BB*NFRAMES)
#define MID_STFT_BLOCKS ((STFT_JOBS+5)/6)
#define MID_BLOCKS (MID_MF + MID_STFT_BLOCKS)

#define RL(x,l) __uint_as_float(__builtin_amdgcn_readlane(__float_as_uint(x), (l)))

#define CH  25
#define NCH 20

// fast activations (v_exp_f32-based, ~2ulp; GRU is contraction-stable so
// 500-step drift ~1e-5 in h -> <<1e-3 in output; margin is 0.054)
__device__ __forceinline__ float fsig(float x){
  return __fdividef(1.0f, 1.0f + __expf(-x));
}
__device__ __forceinline__ float ftanh(float x){
  return fmaf(-2.0f, __fdividef(1.0f, 1.0f + __expf(2.0f*x)), 1.0f);
}

__global__ __launch_bounds__(384) void k_mid(
    const float* __restrict__ gi, const float* __restrict__ Whh,
    const float* __restrict__ bhh, float* __restrict__ gout,
    const float* __restrict__ f0, const float* __restrict__ nL,
    const float* __restrict__ nR, float* __restrict__ ws){
  // GRU LDS: gibuf 2*4800 + hist 4096 + ash 2*192 = 14080 floats (56.3KB)
  __shared__ __align__(16) float sh[14080];
  int blk = blockIdx.x;
  int tid = threadIdx.x;

  if (blk < MID_GRU){
    // ---- GRU: waves 0-2 each own ONE gate (64 resident weights/lane,
    // 64RL+64fmaf issue = 1/3 of the single-wave dot). Wave 3 = gi
    // producer (chunked LDS dbuf, r13). One dbuf-ash barrier per step --
    // cheap now because the recurrence loop has NO vmem ops (r13 learning:
    // barrier drain only costs when vmem outstanding). All gate waves
    // redundantly compute the activation chain (identical hreg). Dot form
    // (4-acc x 16) identical to r12/r13 -> bit-identical dots; only the
    // exp/tanh impl changed (fast, analyzed safe).
    float* gibuf = sh;            // [2][4800]
    float* hist  = sh + 9600;     // [64][64] flat
    float* ash   = sh + 13696;    // [2][192]
    int b = blk;
    int wv = tid >> 6;            // 0..3
    int j = tid & 63;
    float w[64];
    float br=0.f, bz=0.f, bn=0.f;
    if (wv < 3){
      const float* wrow = Whh + (size_t)(wv*64 + j)*64;
      #pragma unroll
      for (int i=0;i<16;i++){
        float4 v = *(const float4*)(wrow + i*4);
        w[4*i]=v.x; w[4*i+1]=v.y; w[4*i+2]=v.z; w[4*i+3]=v.w;
      }
      br = bhh[j]; bz = bhh[64+j]; bn = bhh[128+j];
    }
    const float* gbase = gi + (size_t)b*TT*192;
    if (wv == 3){
      int pt = tid - 192;
      for (int idx = pt; idx < CH*48; idx += 64){
        float4 v = *(const float4*)(gbase + idx*4);
        *(float4*)&gibuf[idx*4] = v;
      }
    }
    __syncthreads();
    float hreg = 0.0f;
    float* op = gout + (size_t)b*TT*64;
    for (int t=0;t<TT;t++){
      int c = t / CH;
      int tt = t - c*CH;
      float gr0=0.f, gz0=0.f, gn0=0.f;
      if (wv < 3){
        // gi reads early (chunk resident since last chunk's barriers)
        const float* gch = &gibuf[(c&1)*4800 + tt*192];
        gr0 = gch[j]; gz0 = gch[64+j]; gn0 = gch[128+j];
        float a0=0.f,a1=0.f,a2=0.f,a3=0.f;
        #pragma unroll
        for (int i=0;i<16;i++){
          a0 = fmaf(w[i],    RL(hreg, i),    a0);
          a1 = fmaf(w[16+i], RL(hreg, 16+i), a1);
          a2 = fmaf(w[32+i], RL(hreg, 32+i), a2);
          a3 = fmaf(w[48+i], RL(hreg, 48+i), a3);
        }
        ash[(t&1)*192 + wv*64 + j] =
            __fadd_rn(__fadd_rn(a0,a1), __fadd_rn(a2,a3));
      } else {
        if (tt == 0 && c+1 < NCH){
          int pt = tid - 192;
          const float* src = gbase + (size_t)(c+1)*CH*192;
          float* dst = &gibuf[((c+1)&1)*4800];
          for (int idx = pt; idx < CH*48; idx += 64){
            float4 v = *(const float4*)(src + idx*4);
            *(float4*)&dst[idx*4] = v;
          }
        }
      }
      __syncthreads();
      if (wv < 3){
        const float* ab = &ash[(t&1)*192];
        float ar = ab[j], az = ab[64+j], an = ab[128+j];
        float r = fsig(gr0 + ar + br);
        float z = fsig(gz0 + az + bz);
        float n = ftanh(gn0 + r*(an+bn));
        hreg = (1.0f - z)*n + z*hreg;       // identical on waves 0-2
        if (wv == 0){
          int th = t & 63;
          hist[th*64 + j] = hreg;
          if (th == 63 || t == TT-1){
            int base_t = t - th;
            int per = th + 1;
            int nb = per >> 2;
            float* dst2 = op + base_t*64 + j*per;
            for (int q=0;q<nb;q++){
              float4 v = *(float4*)&hist[j*per + q*4];
              *(float4*)&dst2[q*4] = v;
            }
          }
        }
      }
    }
  } else if (blk < MID_MF){
    // ---- meanf0 (bit-exact numpy pairwise tree)
    int bk = blk - MID_GRU;
    int b = bk >> 5, k = bk & 31;
    float kf = (float)(k+1);
    float* f0s = sh;
    float* red = sh + 512;
    for (int i=tid;i<TT;i+=384) f0s[i] = f0[b*TT+i];
    __syncthreads();
    if (tid < 256){
      float lv[4];
      #pragma unroll
      for (int q=0;q<4;q++){
        int leafIdx = tid*4 + q;
        int off = 0, n = NSAMP;
        #pragma unroll
        for (int lvl=9; lvl>=0; --lvl){
          int n2 = (n>>1); n2 -= (n2 & 7);
          if ((leafIdx >> lvl) & 1){ off += n2; n -= n2; } else { n = n2; }
        }
        lv[q] = np_block_sum(f0s, off, n, kf);
      }
      red[tid] = __fadd_rn(__fadd_rn(lv[0],lv[1]), __fadd_rn(lv[2],lv[3]));
    }
    __syncthreads();
    for (int cnt=256; cnt>1; cnt>>=1){
      int half = cnt>>1;
      float v = 0.0f;
      if (tid < half) v = __fadd_rn(red[2*tid], red[2*tid+1]);
      __syncthreads();
      if (tid < half) red[tid] = v;
      __syncthreads();
    }
    if (tid==0){
      float mf = __fdiv_rn(red[0], 120000.0f);
      float c1 = __fmul_rn((float)(2.0*M_PI/48000.0), mf);
      ws[OFF_C1 + b*32 + k] = c1;
    }
  } else {
    // ---- STFT: 6 frames per block (one wave each), shared twiddle table
    int base = (blk - MID_MF)*6;
    int sub = tid >> 6;
    int j = tid & 63;
    float2* tw = (float2*)sh;
    float* frs = sh + 512 + sub*256;
    if (tid < 256){
      double a = (2.0*M_PI/256.0)*(double)tid;
      tw[tid] = make_float2((float)cos(a), (float)sin(a));
    }
    int jid = base + sub;
    bool act = jid < STFT_JOBS;
    int b=0, f=0; const float* x = nL;
    if (act){
      int ch = jid / (BB*NFRAMES);
      int rem = jid - ch*(BB*NFRAMES);
      b = rem / NFRAMES; f = rem - b*NFRAMES;
      x = (ch ? nR : nL) + (size_t)b*NSAMP;
      for (int n=j;n<256;n+=64){
        double a = (2.0*M_PI/256.0)*(double)n;
        int xi = f*NHOPF + n - 128;
        xi = xi < 0 ? -xi : xi;
        xi = xi >= NSAMP ? 2*(NSAMP-1)-xi : xi;
        float wnd = (float)(0.5 - 0.5*cos(a));
        frs[n] = x[xi]*wnd;
      }
    }
    __syncthreads();
    if (act){
      int ch = jid / (BB*NFRAMES);
      float* spec = ws + (ch ? OFF_SPECR : OFF_SPECL) + (size_t)(b*NFRAMES+f)*258;
      float re0=0.f, im0=0.f, re1=0.f, im1=0.f;
      int m0 = 0;
      #pragma unroll 4
      for (int n=0;n<256;n++){
        float fv = frs[n];
        int m1 = (m0 + ((n&3)<<6)) & 255;
        float2 t0 = tw[m0], t1 = tw[m1];
        re0 = fmaf(fv, t0.x, re0); im0 = fmaf(-fv, t0.y, im0);
        re1 = fmaf(fv, t1.x, re1); im1 = fmaf(-fv, t1.y, im1);
        m0 = (m0 + j) & 255;
      }
      float pq = frs[j] + frs[j+64] + frs[j+128] + frs[j+192];
      pq = (j & 1) ? -pq : pq;
      for (int o2=32;o2>0;o2>>=1) pq += __shfl_down(pq, o2, 64);
      spec[2*j]   = re0; spec[2*j+1]   = im0;
      spec[2*(j+64)] = re1; spec[2*(j+64)+1] = im1;
      if (j==0){ spec[256] = pq; spec[257] = 0.0f; }
    }
  }
}

// ---------------- fused post matmul + heads ----------------
__global__ __launch_bounds__(128) void k_posthead(const float* __restrict__ gout,
  const float* __restrict__ Wpo, const float* __restrict__ bpo,
  const float* __restrict__ WhL, const float* __restrict__ bhL,
  const float* __restrict__ WhR, const float* __restrict__ bhR,
  const float* __restrict__ Wam, const float* __restrict__ bam,
  const float* __restrict__ WnL, const float* __restrict__ bnL,
  const float* __restrict__ WnR, const float* __restrict__ bnR,
  float* __restrict__ harmL, float* __restrict__ harmR, float* __restrict__ amp,
  float* __restrict__ nmagL, float* __restrict__ nmagR){
  int row = blockIdx.x;
  int tid = threadIdx.x;
  __shared__ float gs[HID];
  __shared__ float post[MLPD];
  if (tid < HID) gs[tid] = gout[(size_t)row*HID + tid];
  __syncthreads();
  {
    const float* wp = Wpo + tid*HID;
    float acc = bpo[tid];
    #pragma unroll 8
    for (int i=0;i<HID;i++) acc = fmaf(gs[i], wp[i], acc);
    post[tid] = fmaxf(acc, 0.0f);
  }
  __syncthreads();
  #pragma unroll
  for (int rr=0;rr<3;rr++){
    int c = tid + rr*128;
    if (c >= 323) break;
    const float* W; const float* bb; float* o; int oc, ow; bool sp=false;
    if (c < 32)      { W=WhL; bb=bhL; o=harmL; oc=c;     ow=32; }
    else if (c < 64) { W=WhR; bb=bhR; o=harmR; oc=c-32;  ow=32; }
    else if (c == 64){ W=Wam; bb=bam; o=amp;   oc=0;     ow=1; sp=true; }
    else if (c < 194){ W=WnL; bb=bnL; o=nmagL; oc=c-65;  ow=129; }
    else             { W=WnR; bb=bnR; o=nmagR; oc=c-194; ow=129; }
    const float* wp = W + oc*MLPD;
    float acc = bb[oc];
    #pragma unroll 8
    for (int i=0;i<MLPD;i++) acc = fmaf(post[i], wp[i], acc);
    float v;
    if (sp) v = fmaxf(acc, 0.0f) + log1pf(expf(-fabsf(acc)));
    else    v = 1.0f/(1.0f+expf(-acc));
    o[(size_t)row*ow + oc] = v;
  }
}

// ---------------- mag filter + irfft + window (IN-PLACE on spec slot) ----------------
__global__ __launch_bounds__(256) void k_istft(float* __restrict__ ws){
  int fr = blockIdx.x;
  int ch = blockIdx.y;
  int b = fr / NFRAMES, f = fr - b*NFRAMES;
  float* spec = ws + (ch ? OFF_SPECR : OFF_SPECL) + (size_t)fr*258;
  const float* nmag = ws + (ch ? OFF_NMAGR : OFF_NMAGL) + (size_t)b*TT*NBIN;
  int t = threadIdx.x;
  __shared__ float2 tw[256];
  __shared__ float2 mx[NBIN];
  double a = (2.0*M_PI/256.0)*(double)t;
  float cz = (float)cos(a), sz = (float)sin(a);
  tw[t] = make_float2(cz, sz);
  if (t < NBIN){
    float pos = ((float)f + 0.5f) * R_MAG - 0.5f;
    pos = fminf(fmaxf(pos, 0.0f), 499.0f);
    int i0 = (int)pos, i1 = min(i0+1, TT-1);
    float w = pos - (float)i0;
    float mg = nmag[i0*NBIN + t]*(1.0f-w) + nmag[i1*NBIN + t]*w;
    mx[t] = make_float2(spec[2*t]*mg, spec[2*t+1]*mg);
  }
  __syncthreads();
  float acc0 = mx[0].x + ((t&1) ? -mx[128].x : mx[128].x);
  float acc = 0.0f;
  int mi = t;
  #pragma unroll 4
  for (int k=1;k<128;k++){
    float2 v = mx[k];
    float2 tk = tw[mi];
    acc = fmaf(v.x, tk.x, acc);
    acc = fmaf(-v.y, tk.y, acc);
    mi = (mi + t) & 255;
  }
  float y = (acc0 + 2.0f*acc) * (1.0f/256.0f);
  float win = 0.5f - 0.5f*cz;
  spec[t] = y*win;
}

// ---------------- final: harmonic synth + OLA gather ----------------
__global__ __launch_bounds__(256) void k_out(const float* __restrict__ f0,
    const float* __restrict__ ws, float* __restrict__ out){
  __shared__ float win2[256];
  __shared__ float c1s[BB*32];
  {
    int t = threadIdx.x;
    double a = (2.0*M_PI/256.0)*(double)t;
    float w = (float)(0.5 - 0.5*cos(a));
    win2[t] = w*w;
    if (t < BB*32) c1s[t] = ws[OFF_C1 + t];
  }
  __syncthreads();
  int idx = blockIdx.x*256 + threadIdx.x;
  if (idx >= BB*2*NSAMP) return;
  int m = idx % NSAMP;
  int bc = idx / NSAMP;
  int ch = bc & 1, b = bc >> 1;
  int i0,i1; float w,w1;
  up_coords(m,&i0,&i1,&w,&w1);
  const float* f0b = f0 + b*TT;
  float f0u = __fadd_rn(__fmul_rn(f0b[i0], w1), __fmul_rn(f0b[i1], w));
  const float* am = ws + OFF_AMP + b*TT;
  float oa = __fadd_rn(__fmul_rn(am[i0], w1), __fmul_rn(am[i1], w));
  const float* ha = ws + (ch ? OFF_HARMR : OFF_HARML) + (size_t)b*TT*NHARM;
  float tm = (float)m;
  float hsum = 0.0f;
  for (int k=1;k<=NHARM;k++){
    float instf = __fmul_rn(f0u, (float)k);
    if (instf < 21600.0f){
      float a0 = ha[i0*NHARM + (k-1)], a1 = ha[i1*NHARM + (k-1)];
      float ak = __fadd_rn(__fmul_rn(a0, w1), __fmul_rn(a1, w));
      float ph = __fmul_rn(c1s[b*32 + (k-1)], tm);
      double rev = (double)ph * 0.15915494309189535;
      double fr2 = rev - floor(rev);
      float rad = (float)((fr2 - (fr2 >= 0.5 ? 1.0 : 0.0)) * 6.283185307179586);
      float s = sinf(rad);
      hsum = __fadd_rn(hsum, __fmul_rn(ak, s));
    }
  }
  float harm = __fmul_rn(hsum, oa);
  int p = m + 128;
  int fhi = min(p >> 6, NFRAMES-1);
  int flo = max((p - 192) >> 6, 0);
  const float* frb = ws + (ch ? OFF_SPECR : OFF_SPECL) + (size_t)b*NFRAMES*258;
  float nacc = 0.0f, wsum = 0.0f;
  for (int f=flo; f<=fhi; f++){
    int n = p - f*NHOPF;
    nacc += frb[f*258 + n];
    wsum += win2[n];
  }
  float noise = nacc / fmaxf(wsum, 1e-11f);
  out[idx] = __fadd_rn(harm, noise);
}

extern "C" void kernel_launch(void* const* d_in, const int* in_sizes, int n_in,
                              void* d_out, int out_size, void* d_ws, size_t ws_size,
                              hipStream_t stream){
  const float* f0  = (const float*)d_in[0];
  const float* ldb = (const float*)d_in[1];
  const float* vel = (const float*)d_in[2];
  const float* nL  = (const float*)d_in[3];
  const float* nR  = (const float*)d_in[4];
  const float* Wp1 = (const float*)d_in[5];
  const float* bp1 = (const float*)d_in[6];
  const float* Wp2 = (const float*)d_in[7];
  const float* bp2 = (const float*)d_in[8];
  const float* Wih = (const float*)d_in[9];
  const float* Whh = (const float*)d_in[10];
  const float* bih = (const float*)d_in[11];
  const float* bhh = (const float*)d_in[12];
  const float* Wpo = (const float*)d_in[13];
  const float* bpo = (const float*)d_in[14];
  const float* WhL = (const float*)d_in[15];
  const float* bhL = (const float*)d_in[16];
  const float* WhR = (const float*)d_in[17];
  const float* bhR = (const float*)d_in[18];
  const float* Wam = (const float*)d_in[19];
  const float* bam = (const float*)d_in[20];
  const float* WnL = (const float*)d_in[21];
  const float* bnL = (const float*)d_in[22];
  const float* WnR = (const float*)d_in[23];
  const float* bnR = (const float*)d_in[24];
  float* ws = (float*)d_ws;
  float* out = (float*)d_out;

  k_encmm<<<BB*TT, 128, 0, stream>>>(f0, ldb, vel, Wp1, bp1, ws+OFF_H1);
  k_mm2gi<<<BB*TT, 192, 0, stream>>>(ws+OFF_H1, Wp2, bp2, Wih, bih, ws+OFF_GI);
  k_mid<<<MID_BLOCKS, 384, 0, stream>>>(ws+OFF_GI, Whh, bhh, ws+OFF_GOUT, f0, nL, nR, ws);
  k_posthead<<<BB*TT, 128, 0, stream>>>(ws+OFF_GOUT, Wpo, bpo,
      WhL,bhL, WhR,bhR, Wam,bam, WnL,bnL, WnR,bnR,
      ws+OFF_HARML, ws+OFF_HARMR, ws+OFF_AMP, ws+OFF_NMAGL, ws+OFF_NMAGR);
  dim3 gs(BB*NFRAMES, 2);
  k_istft<<<gs, 256, 0, stream>>>(ws);
  k_out<<<(BB*2*NSAMP+255)/256, 256, 0, stream>>>(f0, ws, out);
}

// Round 15
// 498.553 us; speedup vs baseline: 1.1933x; 1.1933x over previous
//
#include <hip/hip_runtime.h>
#include <math.h>

#ifndef M_PI
#define M_PI 3.14159265358979323846
#endif

#define BB 4
#define TT 500
#define NSAMP 120000
#define NHARM 32
#define NFFT 256
#define NBIN 129
#define NHOPF 64
#define NFRAMES 1876
#define HID 64
#define MLPD 128
#define FEATD 88

#define R_MAG ((float)(500.0/1876.0))
#define R_UP_F ((float)(500.0/120000.0))

// ---- workspace layout (float offsets) ----
#define OFF_HARML 0
#define OFF_HARMR 64000
#define OFF_AMP   128000
#define OFF_NMAGL 130000
#define OFF_NMAGR 388000
#define OFF_C1    646000
#define OFF_H1    646128
#define OFF_GI    (OFF_H1+256000)
#define OFF_GOUT  (OFF_GI+384000)
#define OFF_SPECL (OFF_GOUT+128000)
#define OFF_SPECR (OFF_SPECL+4*NFRAMES*258)
/* end = 5286160 floats = 21.1 MB */

// f32 upsample position/interp chain, bit-exact to numpy float32 elementwise
__device__ __forceinline__ void up_coords(int m, int* i0, int* i1, float* w, float* w1){
  float pos = __fadd_rn(__fmul_rn(__fadd_rn((float)m, 0.5f), R_UP_F), -0.5f);
  pos = fminf(fmaxf(pos, 0.0f), 499.0f);
  int a = (int)pos;
  *i0 = a; *i1 = min(a+1, TT-1);
  float ww = __fsub_rn(pos, (float)a);
  *w = ww; *w1 = __fsub_rn(1.0f, ww);
}
__device__ __forceinline__ float f0_up_elem(const float* __restrict__ f0s, int m){
  int i0,i1; float w,w1;
  up_coords(m,&i0,&i1,&w,&w1);
  return __fadd_rn(__fmul_rn(f0s[i0], w1), __fmul_rn(f0s[i1], w));
}

// ---------------- fused encoding + pre1 matmul ----------------
__global__ __launch_bounds__(128) void k_encmm(const float* __restrict__ f0,
    const float* __restrict__ ldb, const float* __restrict__ vel,
    const float* __restrict__ Wp1, const float* __restrict__ bp1,
    float* __restrict__ h1){
  int row = blockIdx.x;
  int b = row / TT;
  int tid = threadIdx.x;
  __shared__ float feat[FEATD];
  if (tid < FEATD){
    float f = f0[row];
    float gate = (f > 0.0f) ? 1.0f : 0.0f;
    float fs = fmaxf(f, 20.0f);
    float fn = (logf(fs) - (float)2.995732273553991) / (float)5.5214609178622464;
    fn = fminf(fmaxf(fn, 0.0f), 1.0f);
    float ln = fminf(fmaxf((ldb[row] + 80.0f) / 80.0f, 0.0f), 1.0f);
    float vn = fminf(fmaxf(vel[b] / 7.0f, 0.0f), 1.0f);
    float norm; int i; float g2 = 1.0f;
    if (tid < 64){ i = (tid>>1) + 1; norm = fn; g2 = gate; }
    else if (tid < 80){ i = ((tid-64)>>1) + 1; norm = ln; }
    else { i = ((tid-80)>>1) + 1; norm = vn; }
    float ang = (float)M_PI * (float)i * norm;
    feat[tid] = ((tid & 1) ? cosf(ang) : sinf(ang)) * g2;
  }
  __syncthreads();
  const float* wp = Wp1 + tid*FEATD;
  float acc = bp1[tid];
  #pragma unroll 8
  for (int i=0;i<FEATD;i++) acc = fmaf(feat[i], wp[i], acc);
  h1[(size_t)row*MLPD + tid] = fmaxf(acc, 0.0f);
}

// ---------------- fused pre2 matmul + gi matmul ----------------
__global__ __launch_bounds__(192) void k_mm2gi(const float* __restrict__ h1,
    const float* __restrict__ Wp2, const float* __restrict__ bp2,
    const float* __restrict__ Wih, const float* __restrict__ bih,
    float* __restrict__ gi){
  int row = blockIdx.x;
  int tid = threadIdx.x;
  __shared__ float h1s[MLPD];
  __shared__ float h2s[MLPD];
  if (tid < MLPD) h1s[tid] = h1[(size_t)row*MLPD + tid];
  __syncthreads();
  if (tid < MLPD){
    const float* wp = Wp2 + tid*MLPD;
    float acc = bp2[tid];
    #pragma unroll 8
    for (int i=0;i<MLPD;i++) acc = fmaf(h1s[i], wp[i], acc);
    h2s[tid] = fmaxf(acc, 0.0f);
  }
  __syncthreads();
  const float* wp = Wih + tid*MLPD;
  float acc = bih[tid];
  #pragma unroll 8
  for (int i=0;i<MLPD;i++) acc = fmaf(h2s[i], wp[i], acc);
  gi[(size_t)row*192 + tid] = acc;
}

// numpy-exact pairwise block sum (leaf of the depth-10 perfect tree)
__device__ float np_block_sum(const float* __restrict__ f0s, int off, int n, float kf){
  float r[8];
  #pragma unroll
  for (int j=0;j<8;j++) r[j] = __fmul_rn(f0_up_elem(f0s, off+j), kf);
  int lim = n - (n & 7);
  int i = 8;
  for (; i<lim; i+=8){
    #pragma unroll
    for (int j=0;j<8;j++)
      r[j] = __fadd_rn(r[j], __fmul_rn(f0_up_elem(f0s, off+i+j), kf));
  }
  float res = __fadd_rn(__fadd_rn(__fadd_rn(r[0],r[1]), __fadd_rn(r[2],r[3])),
                        __fadd_rn(__fadd_rn(r[4],r[5]), __fadd_rn(r[6],r[7])));
  for (; i<n; i++)
    res = __fadd_rn(res, __fmul_rn(f0_up_elem(f0s, off+i), kf));
  return res;
}

// ---------------- fused mid: GRU + STFT + meanf0 ----------------
#define MID_GRU   BB
#define MID_MF    (MID_GRU + BB*32)
#define STFT_JOBS (2*BB*NFRAMES)
#define MID_STFT_BLOCKS ((STFT_JOBS+5)/6)
#define MID_BLOCKS (MID_MF + MID_STFT_BLOCKS)

#define RL(x,l) __uint_as_float(__builtin_amdgcn_readlane(__float_as_uint(x), (l)))

#define CH  25
#define NCH 20

// fast activations (v_exp_f32-based, ~2ulp). VALIDATED r14: absmax stayed
// EXACTLY 0.1135254 with these (max error lives in the phase path, not GRU).
__device__ __forceinline__ float fsig(float x){
  return __fdividef(1.0f, 1.0f + __expf(-x));
}
__device__ __forceinline__ float ftanh(float x){
  return fmaf(-2.0f, __fdividef(1.0f, 1.0f + __expf(2.0f*x)), 1.0f);
}

__global__ __launch_bounds__(384) void k_mid(
    const float* __restrict__ gi, const float* __restrict__ Whh,
    const float* __restrict__ bhh, float* __restrict__ gout,
    const float* __restrict__ f0, const float* __restrict__ nL,
    const float* __restrict__ nR, float* __restrict__ ws){
  // GRU LDS: gibuf 2*4800 + hist 4096 = 13696 floats (54.8KB)
  __shared__ __align__(16) float sh[13696];
  int blk = blockIdx.x;
  int tid = threadIdx.x;

  if (blk < MID_GRU){
    // ---- GRU (r13 structure, r15 = +fast activations): consumer wave
    // (tid<64) free-runs the recurrence with gi served from LDS; 3 producer
    // waves double-buffer gi chunks one ahead. Barriers ONLY at the 20
    // chunk bounds (r14 lesson: per-step barriers + producer vmcnt drain
    // cost ~100ns/step + 900cyc/chunk). Dot verbatim r12/r13 (bit-ident).
    float* gibuf = sh;            // [2][4800]
    float* hist  = sh + 9600;     // [64][64]
    int b = blk;
    int j = tid & 63;
    float wr[64], wz[64], wn[64];
    float br=0.f, bz=0.f, bn=0.f;
    if (tid < 64){
      #pragma unroll
      for (int i=0;i<16;i++){
        float4 a = *(const float4*)(Whh + (size_t)(j)*64     + i*4);
        float4 c = *(const float4*)(Whh + (size_t)(64+j)*64  + i*4);
        float4 d = *(const float4*)(Whh + (size_t)(128+j)*64 + i*4);
        wr[4*i]=a.x; wr[4*i+1]=a.y; wr[4*i+2]=a.z; wr[4*i+3]=a.w;
        wz[4*i]=c.x; wz[4*i+1]=c.y; wz[4*i+2]=c.z; wz[4*i+3]=c.w;
        wn[4*i]=d.x; wn[4*i+1]=d.y; wn[4*i+2]=d.z; wn[4*i+3]=d.w;
      }
      br = bhh[j]; bz = bhh[64+j]; bn = bhh[128+j];
    }
    const float* gbase = gi + (size_t)b*TT*192;
    // stage chunk 0
    if (tid >= 64){
      int pt = tid - 64;
      for (int idx = pt; idx < CH*48; idx += 192){
        float4 v = *(const float4*)(gbase + idx*4);
        *(float4*)&gibuf[idx*4] = v;
      }
    }
    __syncthreads();
    float hreg = 0.0f;
    float* op = gout + (size_t)b*TT*64;
    for (int c=0; c<NCH; c++){
      if (tid >= 64){
        if (c+1 < NCH){
          int pt = tid - 64;
          const float* src = gbase + (size_t)(c+1)*CH*192;
          float* dst = &gibuf[((c+1)&1)*4800];
          for (int idx = pt; idx < CH*48; idx += 192){
            float4 v = *(const float4*)(src + idx*4);
            *(float4*)&dst[idx*4] = v;
          }
        }
      } else {
        const float* gch = &gibuf[(c&1)*4800];
        for (int tt=0; tt<CH; tt++){
          int t = c*CH + tt;
          float gr0 = gch[tt*192 + j];
          float gz0 = gch[tt*192 + 64 + j];
          float gn0 = gch[tt*192 + 128 + j];
          float ar0=0.f,ar1=0.f,ar2=0.f,ar3=0.f;
          float az0=0.f,az1=0.f,az2=0.f,az3=0.f;
          float an0=0.f,an1=0.f,an2=0.f,an3=0.f;
          #pragma unroll
          for (int i=0;i<16;i++){
            float h0 = RL(hreg, i), h1v = RL(hreg, 16+i);
            float h2v = RL(hreg, 32+i), h3v = RL(hreg, 48+i);
            ar0 = fmaf(wr[i],    h0,  ar0); ar1 = fmaf(wr[16+i], h1v, ar1);
            ar2 = fmaf(wr[32+i], h2v, ar2); ar3 = fmaf(wr[48+i], h3v, ar3);
            az0 = fmaf(wz[i],    h0,  az0); az1 = fmaf(wz[16+i], h1v, az1);
            az2 = fmaf(wz[32+i], h2v, az2); az3 = fmaf(wz[48+i], h3v, az3);
            an0 = fmaf(wn[i],    h0,  an0); an1 = fmaf(wn[16+i], h1v, an1);
            an2 = fmaf(wn[32+i], h2v, an2); an3 = fmaf(wn[48+i], h3v, an3);
          }
          float ar = __fadd_rn(__fadd_rn(ar0,ar1), __fadd_rn(ar2,ar3));
          float az = __fadd_rn(__fadd_rn(az0,az1), __fadd_rn(az2,az3));
          float an = __fadd_rn(__fadd_rn(an0,an1), __fadd_rn(an2,an3));
          float r = fsig(gr0 + ar + br);
          float z = fsig(gz0 + az + bz);
          float n = ftanh(gn0 + r*(an+bn));
          hreg = (1.0f - z)*n + z*hreg;
          int th = t & 63;
          hist[th*64 + j] = hreg;
          if (th == 63 || t == TT-1){
            int base_t = t - th;
            int per = th + 1;
            int nb = per >> 2;
            float* dst2 = op + base_t*64 + j*per;
            for (int q=0;q<nb;q++){
              float4 v = *(float4*)&hist[j*per + q*4];
              *(float4*)&dst2[q*4] = v;
            }
          }
        }
      }
      __syncthreads();
    }
  } else if (blk < MID_MF){
    // ---- meanf0 (bit-exact numpy pairwise tree)
    int bk = blk - MID_GRU;
    int b = bk >> 5, k = bk & 31;
    float kf = (float)(k+1);
    float* f0s = sh;
    float* red = sh + 512;
    for (int i=tid;i<TT;i+=384) f0s[i] = f0[b*TT+i];
    __syncthreads();
    if (tid < 256){
      float lv[4];
      #pragma unroll
      for (int q=0;q<4;q++){
        int leafIdx = tid*4 + q;
        int off = 0, n = NSAMP;
        #pragma unroll
        for (int lvl=9; lvl>=0; --lvl){
          int n2 = (n>>1); n2 -= (n2 & 7);
          if ((leafIdx >> lvl) & 1){ off += n2; n -= n2; } else { n = n2; }
        }
        lv[q] = np_block_sum(f0s, off, n, kf);
      }
      red[tid] = __fadd_rn(__fadd_rn(lv[0],lv[1]), __fadd_rn(lv[2],lv[3]));
    }
    __syncthreads();
    for (int cnt=256; cnt>1; cnt>>=1){
      int half = cnt>>1;
      float v = 0.0f;
      if (tid < half) v = __fadd_rn(red[2*tid], red[2*tid+1]);
      __syncthreads();
      if (tid < half) red[tid] = v;
      __syncthreads();
    }
    if (tid==0){
      float mf = __fdiv_rn(red[0], 120000.0f);
      float c1 = __fmul_rn((float)(2.0*M_PI/48000.0), mf);
      ws[OFF_C1 + b*32 + k] = c1;
    }
  } else {
    // ---- STFT: 6 frames per block (one wave each), shared twiddle table
    int base = (blk - MID_MF)*6;
    int sub = tid >> 6;
    int j = tid & 63;
    float2* tw = (float2*)sh;
    float* frs = sh + 512 + sub*256;
    if (tid < 256){
      double a = (2.0*M_PI/256.0)*(double)tid;
      tw[tid] = make_float2((float)cos(a), (float)sin(a));
    }
    int jid = base + sub;
    bool act = jid < STFT_JOBS;
    int b=0, f=0; const float* x = nL;
    if (act){
      int ch = jid / (BB*NFRAMES);
      int rem = jid - ch*(BB*NFRAMES);
      b = rem / NFRAMES; f = rem - b*NFRAMES;
      x = (ch ? nR : nL) + (size_t)b*NSAMP;
      for (int n=j;n<256;n+=64){
        double a = (2.0*M_PI/256.0)*(double)n;
        int xi = f*NHOPF + n - 128;
        xi = xi < 0 ? -xi : xi;
        xi = xi >= NSAMP ? 2*(NSAMP-1)-xi : xi;
        float wnd = (float)(0.5 - 0.5*cos(a));
        frs[n] = x[xi]*wnd;
      }
    }
    __syncthreads();
    if (act){
      int ch = jid / (BB*NFRAMES);
      float* spec = ws + (ch ? OFF_SPECR : OFF_SPECL) + (size_t)(b*NFRAMES+f)*258;
      float re0=0.f, im0=0.f, re1=0.f, im1=0.f;
      int m0 = 0;
      #pragma unroll 4
      for (int n=0;n<256;n++){
        float fv = frs[n];
        int m1 = (m0 + ((n&3)<<6)) & 255;
        float2 t0 = tw[m0], t1 = tw[m1];
        re0 = fmaf(fv, t0.x, re0); im0 = fmaf(-fv, t0.y, im0);
        re1 = fmaf(fv, t1.x, re1); im1 = fmaf(-fv, t1.y, im1);
        m0 = (m0 + j) & 255;
      }
      float pq = frs[j] + frs[j+64] + frs[j+128] + frs[j+192];
      pq = (j & 1) ? -pq : pq;
      for (int o2=32;o2>0;o2>>=1) pq += __shfl_down(pq, o2, 64);
      spec[2*j]   = re0; spec[2*j+1]   = im0;
      spec[2*(j+64)] = re1; spec[2*(j+64)+1] = im1;
      if (j==0){ spec[256] = pq; spec[257] = 0.0f; }
    }
  }
}

// ---------------- fused post matmul + heads ----------------
__global__ __launch_bounds__(128) void k_posthead(const float* __restrict__ gout,
  const float* __restrict__ Wpo, const float* __restrict__ bpo,
  const float* __restrict__ WhL, const float* __restrict__ bhL,
  const float* __restrict__ WhR, const float* __restrict__ bhR,
  const float* __restrict__ Wam, const float* __restrict__ bam,
  const float* __restrict__ WnL, const float* __restrict__ bnL,
  const float* __restrict__ WnR, const float* __restrict__ bnR,
  float* __restrict__ harmL, float* __restrict__ harmR, float* __restrict__ amp,
  float* __restrict__ nmagL, float* __restrict__ nmagR){
  int row = blockIdx.x;
  int tid = threadIdx.x;
  __shared__ float gs[HID];
  __shared__ float post[MLPD];
  if (tid < HID) gs[tid] = gout[(size_t)row*HID + tid];
  __syncthreads();
  {
    const float* wp = Wpo + tid*HID;
    float acc = bpo[tid];
    #pragma unroll 8
    for (int i=0;i<HID;i++) acc = fmaf(gs[i], wp[i], acc);
    post[tid] = fmaxf(acc, 0.0f);
  }
  __syncthreads();
  #pragma unroll
  for (int rr=0;rr<3;rr++){
    int c = tid + rr*128;
    if (c >= 323) break;
    const float* W; const float* bb; float* o; int oc, ow; bool sp=false;
    if (c < 32)      { W=WhL; bb=bhL; o=harmL; oc=c;     ow=32; }
    else if (c < 64) { W=WhR; bb=bhR; o=harmR; oc=c-32;  ow=32; }
    else if (c == 64){ W=Wam; bb=bam; o=amp;   oc=0;     ow=1; sp=true; }
    else if (c < 194){ W=WnL; bb=bnL; o=nmagL; oc=c-65;  ow=129; }
    else             { W=WnR; bb=bnR; o=nmagR; oc=c-194; ow=129; }
    const float* wp = W + oc*MLPD;
    float acc = bb[oc];
    #pragma unroll 8
    for (int i=0;i<MLPD;i++) acc = fmaf(post[i], wp[i], acc);
    float v;
    if (sp) v = fmaxf(acc, 0.0f) + log1pf(expf(-fabsf(acc)));
    else    v = 1.0f/(1.0f+expf(-acc));
    o[(size_t)row*ow + oc] = v;
  }
}

// ---------------- mag filter + irfft + window (IN-PLACE on spec slot) ----------------
__global__ __launch_bounds__(256) void k_istft(float* __restrict__ ws){
  int fr = blockIdx.x;
  int ch = blockIdx.y;
  int b = fr / NFRAMES, f = fr - b*NFRAMES;
  float* spec = ws + (ch ? OFF_SPECR : OFF_SPECL) + (size_t)fr*258;
  const float* nmag = ws + (ch ? OFF_NMAGR : OFF_NMAGL) + (size_t)b*TT*NBIN;
  int t = threadIdx.x;
  __shared__ float2 tw[256];
  __shared__ float2 mx[NBIN];
  double a = (2.0*M_PI/256.0)*(double)t;
  float cz = (float)cos(a), sz = (float)sin(a);
  tw[t] = make_float2(cz, sz);
  if (t < NBIN){
    float pos = ((float)f + 0.5f) * R_MAG - 0.5f;
    pos = fminf(fmaxf(pos, 0.0f), 499.0f);
    int i0 = (int)pos, i1 = min(i0+1, TT-1);
    float w = pos - (float)i0;
    float mg = nmag[i0*NBIN + t]*(1.0f-w) + nmag[i1*NBIN + t]*w;
    mx[t] = make_float2(spec[2*t]*mg, spec[2*t+1]*mg);
  }
  __syncthreads();
  float acc0 = mx[0].x + ((t&1) ? -mx[128].x : mx[128].x);
  float acc = 0.0f;
  int mi = t;
  #pragma unroll 4
  for (int k=1;k<128;k++){
    float2 v = mx[k];
    float2 tk = tw[mi];
    acc = fmaf(v.x, tk.x, acc);
    acc = fmaf(-v.y, tk.y, acc);
    mi = (mi + t) & 255;
  }
  float y = (acc0 + 2.0f*acc) * (1.0f/256.0f);
  float win = 0.5f - 0.5f*cz;
  spec[t] = y*win;
}

// ---------------- final: harmonic synth + OLA gather ----------------
__global__ __launch_bounds__(256) void k_out(const float* __restrict__ f0,
    const float* __restrict__ ws, float* __restrict__ out){
  __shared__ float win2[256];
  __shared__ float c1s[BB*32];
  {
    int t = threadIdx.x;
    double a = (2.0*M_PI/256.0)*(double)t;
    float w = (float)(0.5 - 0.5*cos(a));
    win2[t] = w*w;
    if (t < BB*32) c1s[t] = ws[OFF_C1 + t];
  }
  __syncthreads();
  int idx = blockIdx.x*256 + threadIdx.x;
  if (idx >= BB*2*NSAMP) return;
  int m = idx % NSAMP;
  int bc = idx / NSAMP;
  int ch = bc & 1, b = bc >> 1;
  int i0,i1; float w,w1;
  up_coords(m,&i0,&i1,&w,&w1);
  const float* f0b = f0 + b*TT;
  float f0u = __fadd_rn(__fmul_rn(f0b[i0], w1), __fmul_rn(f0b[i1], w));
  const float* am = ws + OFF_AMP + b*TT;
  float oa = __fadd_rn(__fmul_rn(am[i0], w1), __fmul_rn(am[i1], w));
  const float* ha = ws + (ch ? OFF_HARMR : OFF_HARML) + (size_t)b*TT*NHARM;
  float tm = (float)m;
  float hsum = 0.0f;
  for (int k=1;k<=NHARM;k++){
    float instf = __fmul_rn(f0u, (float)k);
    if (instf < 21600.0f){
      float a0 = ha[i0*NHARM + (k-1)], a1 = ha[i1*NHARM + (k-1)];
      float ak = __fadd_rn(__fmul_rn(a0, w1), __fmul_rn(a1, w));
      float ph = __fmul_rn(c1s[b*32 + (k-1)], tm);
      double rev = (double)ph * 0.15915494309189535;
      double fr2 = rev - floor(rev);
      float rad = (float)((fr2 - (fr2 >= 0.5 ? 1.0 : 0.0)) * 6.283185307179586);
      float s = sinf(rad);
      hsum = __fadd_rn(hsum, __fmul_rn(ak, s));
    }
  }
  float harm = __fmul_rn(hsum, oa);
  int p = m + 128;
  int fhi = min(p >> 6, NFRAMES-1);
  int flo = max((p - 192) >> 6, 0);
  const float* frb = ws + (ch ? OFF_SPECR : OFF_SPECL) + (size_t)b*NFRAMES*258;
  float nacc = 0.0f, wsum = 0.0f;
  for (int f=flo; f<=fhi; f++){
    int n = p - f*NHOPF;
    nacc += frb[f*258 + n];
    wsum += win2[n];
  }
  float noise = nacc / fmaxf(wsum, 1e-11f);
  out[idx] = __fadd_rn(harm, noise);
}

extern "C" void kernel_launch(void* const* d_in, const int* in_sizes, int n_in,
                              void* d_out, int out_size, void* d_ws, size_t ws_size,
                              hipStream_t stream){
  const float* f0  = (const float*)d_in[0];
  const float* ldb = (const float*)d_in[1];
  const float* vel = (const float*)d_in[2];
  const float* nL  = (const float*)d_in[3];
  const float* nR  = (const float*)d_in[4];
  const float* Wp1 = (const float*)d_in[5];
  const float* bp1 = (const float*)d_in[6];
  const float* Wp2 = (const float*)d_in[7];
  const float* bp2 = (const float*)d_in[8];
  const float* Wih = (const float*)d_in[9];
  const float* Whh = (const float*)d_in[10];
  const float* bih = (const float*)d_in[11];
  const float* bhh = (const float*)d_in[12];
  const float* Wpo = (const float*)d_in[13];
  const float* bpo = (const float*)d_in[14];
  const float* WhL = (const float*)d_in[15];
  const float* bhL = (const float*)d_in[16];
  const float* WhR = (const float*)d_in[17];
  const float* bhR = (const float*)d_in[18];
  const float* Wam = (const float*)d_in[19];
  const float* bam = (const float*)d_in[20];
  const float* WnL = (const float*)d_in[21];
  const float* bnL = (const float*)d_in[22];
  const float* WnR = (const float*)d_in[23];
  const float* bnR = (const float*)d_in[24];
  float* ws = (float*)d_ws;
  float* out = (float*)d_out;

  k_encmm<<<BB*TT, 128, 0, stream>>>(f0, ldb, vel, Wp1, bp1, ws+OFF_H1);
  k_mm2gi<<<BB*TT, 192, 0, stream>>>(ws+OFF_H1, Wp2, bp2, Wih, bih, ws+OFF_GI);
  k_mid<<<MID_BLOCKS, 384, 0, stream>>>(ws+OFF_GI, Whh, bhh, ws+OFF_GOUT, f0, nL, nR, ws);
  k_posthead<<<BB*TT, 128, 0, stream>>>(ws+OFF_GOUT, Wpo, bpo,
      WhL,bhL, WhR,bhR, Wam,bam, WnL,bnL, WnR,bnR,
      ws+OFF_HARML, ws+OFF_HARMR, ws+OFF_AMP, ws+OFF_NMAGL, ws+OFF_NMAGR);
  dim3 gs(BB*NFRAMES, 2);
  k_istft<<<gs, 256, 0, stream>>>(ws);
  k_out<<<(BB*2*NSAMP+255)/256, 256, 0, stream>>>(f0, ws, out);
}

// Round 16
// 456.990 us; speedup vs baseline: 1.3018x; 1.0909x over previous
//
#include <hip/hip_runtime.h>
#include <math.h>

#ifndef M_PI
#define M_PI 3.14159265358979323846
#endif

#define BB 4
#define TT 500
#define NSAMP 120000
#define NHARM 32
#define NFFT 256
#define NBIN 129
#define NHOPF 64
#define NFRAMES 1876
#define HID 64
#define MLPD 128
#define FEATD 88

#define R_MAG ((float)(500.0/1876.0))
#define R_UP_F ((float)(500.0/120000.0))

// ---- workspace layout (float offsets) ----
#define OFF_HARML 0
#define OFF_HARMR 64000
#define OFF_AMP   128000
#define OFF_NMAGL 130000
#define OFF_NMAGR 388000
#define OFF_C1    646000
#define OFF_H1    646128
#define OFF_GI    (OFF_H1+256000)
#define OFF_GOUT  (OFF_GI+384000)
#define OFF_SPECL (OFF_GOUT+128000)
#define OFF_SPECR (OFF_SPECL+4*NFRAMES*258)
/* end = 5286160 floats = 21.1 MB */

// f32 upsample position/interp chain, bit-exact to numpy float32 elementwise
__device__ __forceinline__ void up_coords(int m, int* i0, int* i1, float* w, float* w1){
  float pos = __fadd_rn(__fmul_rn(__fadd_rn((float)m, 0.5f), R_UP_F), -0.5f);
  pos = fminf(fmaxf(pos, 0.0f), 499.0f);
  int a = (int)pos;
  *i0 = a; *i1 = min(a+1, TT-1);
  float ww = __fsub_rn(pos, (float)a);
  *w = ww; *w1 = __fsub_rn(1.0f, ww);
}
__device__ __forceinline__ float f0_up_elem(const float* __restrict__ f0s, int m){
  int i0,i1; float w,w1;
  up_coords(m,&i0,&i1,&w,&w1);
  return __fadd_rn(__fmul_rn(f0s[i0], w1), __fmul_rn(f0s[i1], w));
}

// ---------------- fused encoding + pre1 matmul ----------------
__global__ __launch_bounds__(128) void k_encmm(const float* __restrict__ f0,
    const float* __restrict__ ldb, const float* __restrict__ vel,
    const float* __restrict__ Wp1, const float* __restrict__ bp1,
    float* __restrict__ h1){
  int row = blockIdx.x;
  int b = row / TT;
  int tid = threadIdx.x;
  __shared__ float feat[FEATD];
  if (tid < FEATD){
    float f = f0[row];
    float gate = (f > 0.0f) ? 1.0f : 0.0f;
    float fs = fmaxf(f, 20.0f);
    float fn = (logf(fs) - (float)2.995732273553991) / (float)5.5214609178622464;
    fn = fminf(fmaxf(fn, 0.0f), 1.0f);
    float ln = fminf(fmaxf((ldb[row] + 80.0f) / 80.0f, 0.0f), 1.0f);
    float vn = fminf(fmaxf(vel[b] / 7.0f, 0.0f), 1.0f);
    float norm; int i; float g2 = 1.0f;
    if (tid < 64){ i = (tid>>1) + 1; norm = fn; g2 = gate; }
    else if (tid < 80){ i = ((tid-64)>>1) + 1; norm = ln; }
    else { i = ((tid-80)>>1) + 1; norm = vn; }
    float ang = (float)M_PI * (float)i * norm;
    feat[tid] = ((tid & 1) ? cosf(ang) : sinf(ang)) * g2;
  }
  __syncthreads();
  const float* wp = Wp1 + tid*FEATD;
  float acc = bp1[tid];
  #pragma unroll 8
  for (int i=0;i<FEATD;i++) acc = fmaf(feat[i], wp[i], acc);
  h1[(size_t)row*MLPD + tid] = fmaxf(acc, 0.0f);
}

// ---------------- fused pre2 matmul + gi matmul ----------------
__global__ __launch_bounds__(192) void k_mm2gi(const float* __restrict__ h1,
    const float* __restrict__ Wp2, const float* __restrict__ bp2,
    const float* __restrict__ Wih, const float* __restrict__ bih,
    float* __restrict__ gi){
  int row = blockIdx.x;
  int tid = threadIdx.x;
  __shared__ float h1s[MLPD];
  __shared__ float h2s[MLPD];
  if (tid < MLPD) h1s[tid] = h1[(size_t)row*MLPD + tid];
  __syncthreads();
  if (tid < MLPD){
    const float* wp = Wp2 + tid*MLPD;
    float acc = bp2[tid];
    #pragma unroll 8
    for (int i=0;i<MLPD;i++) acc = fmaf(h1s[i], wp[i], acc);
    h2s[tid] = fmaxf(acc, 0.0f);
  }
  __syncthreads();
  const float* wp = Wih + tid*MLPD;
  float acc = bih[tid];
  #pragma unroll 8
  for (int i=0;i<MLPD;i++) acc = fmaf(h2s[i], wp[i], acc);
  gi[(size_t)row*192 + tid] = acc;
}

// numpy-exact pairwise block sum (leaf of the depth-10 perfect tree)
__device__ float np_block_sum(const float* __restrict__ f0s, int off, int n, float kf){
  float r[8];
  #pragma unroll
  for (int j=0;j<8;j++) r[j] = __fmul_rn(f0_up_elem(f0s, off+j), kf);
  int lim = n - (n & 7);
  int i = 8;
  for (; i<lim; i+=8){
    #pragma unroll
    for (int j=0;j<8;j++)
      r[j] = __fadd_rn(r[j], __fmul_rn(f0_up_elem(f0s, off+i+j), kf));
  }
  float res = __fadd_rn(__fadd_rn(__fadd_rn(r[0],r[1]), __fadd_rn(r[2],r[3])),
                        __fadd_rn(__fadd_rn(r[4],r[5]), __fadd_rn(r[6],r[7])));
  for (; i<n; i++)
    res = __fadd_rn(res, __fmul_rn(f0_up_elem(f0s, off+i), kf));
  return res;
}

// ---------------- fused mid: GRU + STFT + meanf0 ----------------
#define MID_GRU   BB
#define MID_MF    (MID_GRU + BB*32)
#define STFT_JOBS (2*BB*NFRAMES)
#define MID_STFT_BLOCKS ((STFT_JOBS+5)/6)
#define MID_BLOCKS (MID_MF + MID_STFT_BLOCKS)

#define RL(x,l) __uint_as_float(__builtin_amdgcn_readlane(__float_as_uint(x), (l)))

#define CH  25
#define NCH 20

// fast activations (v_exp_f32-based, ~2ulp). VALIDATED r14/r15: absmax stayed
// EXACTLY 0.1135254 (max error lives in the phase path, not the GRU).
__device__ __forceinline__ float fsig(float x){
  return __fdividef(1.0f, 1.0f + __expf(-x));
}
__device__ __forceinline__ float ftanh(float x){
  return fmaf(-2.0f, __fdividef(1.0f, 1.0f + __expf(2.0f*x)), 1.0f);
}

__global__ __launch_bounds__(384) void k_mid(
    const float* __restrict__ gi, const float* __restrict__ Whh,
    const float* __restrict__ bhh, float* __restrict__ gout,
    const float* __restrict__ f0, const float* __restrict__ nL,
    const float* __restrict__ nR, float* __restrict__ ws){
  // GRU LDS: gibuf 2*4800 + hist 4096 = 13696 floats (54.8KB)
  __shared__ __align__(16) float sh[13696];
  int blk = blockIdx.x;
  int tid = threadIdx.x;

  if (blk < MID_GRU){
    // ---- GRU (r13 structure + fast activations): consumer wave free-runs
    // the recurrence from LDS-staged gi; 3 producer waves double-buffer gi
    // chunks one ahead. Barriers ONLY at the 20 chunk bounds.
    float* gibuf = sh;            // [2][4800]
    float* hist  = sh + 9600;     // [64][64]
    int b = blk;
    int j = tid & 63;
    float wr[64], wz[64], wn[64];
    float br=0.f, bz=0.f, bn=0.f;
    if (tid < 64){
      #pragma unroll
      for (int i=0;i<16;i++){
        float4 a = *(const float4*)(Whh + (size_t)(j)*64     + i*4);
        float4 c = *(const float4*)(Whh + (size_t)(64+j)*64  + i*4);
        float4 d = *(const float4*)(Whh + (size_t)(128+j)*64 + i*4);
        wr[4*i]=a.x; wr[4*i+1]=a.y; wr[4*i+2]=a.z; wr[4*i+3]=a.w;
        wz[4*i]=c.x; wz[4*i+1]=c.y; wz[4*i+2]=c.z; wz[4*i+3]=c.w;
        wn[4*i]=d.x; wn[4*i+1]=d.y; wn[4*i+2]=d.z; wn[4*i+3]=d.w;
      }
      br = bhh[j]; bz = bhh[64+j]; bn = bhh[128+j];
    }
    const float* gbase = gi + (size_t)b*TT*192;
    // stage chunk 0
    if (tid >= 64){
      int pt = tid - 64;
      for (int idx = pt; idx < CH*48; idx += 192){
        float4 v = *(const float4*)(gbase + idx*4);
        *(float4*)&gibuf[idx*4] = v;
      }
    }
    __syncthreads();
    float hreg = 0.0f;
    float* op = gout + (size_t)b*TT*64;
    for (int c=0; c<NCH; c++){
      if (tid >= 64){
        if (c+1 < NCH){
          int pt = tid - 64;
          const float* src = gbase + (size_t)(c+1)*CH*192;
          float* dst = &gibuf[((c+1)&1)*4800];
          for (int idx = pt; idx < CH*48; idx += 192){
            float4 v = *(const float4*)(src + idx*4);
            *(float4*)&dst[idx*4] = v;
          }
        }
      } else {
        const float* gch = &gibuf[(c&1)*4800];
        for (int tt=0; tt<CH; tt++){
          int t = c*CH + tt;
          float gr0 = gch[tt*192 + j];
          float gz0 = gch[tt*192 + 64 + j];
          float gn0 = gch[tt*192 + 128 + j];
          float ar0=0.f,ar1=0.f,ar2=0.f,ar3=0.f;
          float az0=0.f,az1=0.f,az2=0.f,az3=0.f;
          float an0=0.f,an1=0.f,an2=0.f,an3=0.f;
          #pragma unroll
          for (int i=0;i<16;i++){
            float h0 = RL(hreg, i), h1v = RL(hreg, 16+i);
            float h2v = RL(hreg, 32+i), h3v = RL(hreg, 48+i);
            ar0 = fmaf(wr[i],    h0,  ar0); ar1 = fmaf(wr[16+i], h1v, ar1);
            ar2 = fmaf(wr[32+i], h2v, ar2); ar3 = fmaf(wr[48+i], h3v, ar3);
            az0 = fmaf(wz[i],    h0,  az0); az1 = fmaf(wz[16+i], h1v, az1);
            az2 = fmaf(wz[32+i], h2v, az2); az3 = fmaf(wz[48+i], h3v, az3);
            an0 = fmaf(wn[i],    h0,  an0); an1 = fmaf(wn[16+i], h1v, an1);
            an2 = fmaf(wn[32+i], h2v, an2); an3 = fmaf(wn[48+i], h3v, an3);
          }
          float ar = __fadd_rn(__fadd_rn(ar0,ar1), __fadd_rn(ar2,ar3));
          float az = __fadd_rn(__fadd_rn(az0,az1), __fadd_rn(az2,az3));
          float an = __fadd_rn(__fadd_rn(an0,an1), __fadd_rn(an2,an3));
          float r = fsig(gr0 + ar + br);
          float z = fsig(gz0 + az + bz);
          float n = ftanh(gn0 + r*(an+bn));
          hreg = (1.0f - z)*n + z*hreg;
          int th = t & 63;
          hist[th*64 + j] = hreg;
          if (th == 63 || t == TT-1){
            int base_t = t - th;
            int per = th + 1;
            int nb = per >> 2;
            float* dst2 = op + base_t*64 + j*per;
            for (int q=0;q<nb;q++){
              float4 v = *(float4*)&hist[j*per + q*4];
              *(float4*)&dst2[q*4] = v;
            }
          }
        }
      }
      __syncthreads();
    }
  } else if (blk < MID_MF){
    // ---- meanf0 (bit-exact numpy pairwise tree)
    int bk = blk - MID_GRU;
    int b = bk >> 5, k = bk & 31;
    float kf = (float)(k+1);
    float* f0s = sh;
    float* red = sh + 512;
    for (int i=tid;i<TT;i+=384) f0s[i] = f0[b*TT+i];
    __syncthreads();
    if (tid < 256){
      float lv[4];
      #pragma unroll
      for (int q=0;q<4;q++){
        int leafIdx = tid*4 + q;
        int off = 0, n = NSAMP;
        #pragma unroll
        for (int lvl=9; lvl>=0; --lvl){
          int n2 = (n>>1); n2 -= (n2 & 7);
          if ((leafIdx >> lvl) & 1){ off += n2; n -= n2; } else { n = n2; }
        }
        lv[q] = np_block_sum(f0s, off, n, kf);
      }
      red[tid] = __fadd_rn(__fadd_rn(lv[0],lv[1]), __fadd_rn(lv[2],lv[3]));
    }
    __syncthreads();
    for (int cnt=256; cnt>1; cnt>>=1){
      int half = cnt>>1;
      float v = 0.0f;
      if (tid < half) v = __fadd_rn(red[2*tid], red[2*tid+1]);
      __syncthreads();
      if (tid < half) red[tid] = v;
      __syncthreads();
    }
    if (tid==0){
      float mf = __fdiv_rn(red[0], 120000.0f);
      float c1 = __fmul_rn((float)(2.0*M_PI/48000.0), mf);
      ws[OFF_C1 + b*32 + k] = c1;
    }
  } else {
    // ---- STFT: 6 frames per block (one wave each), shared twiddle table
    int base = (blk - MID_MF)*6;
    int sub = tid >> 6;
    int j = tid & 63;
    float2* tw = (float2*)sh;
    float* frs = sh + 512 + sub*256;
    if (tid < 256){
      double a = (2.0*M_PI/256.0)*(double)tid;
      tw[tid] = make_float2((float)cos(a), (float)sin(a));
    }
    int jid = base + sub;
    bool act = jid < STFT_JOBS;
    int b=0, f=0; const float* x = nL;
    if (act){
      int ch = jid / (BB*NFRAMES);
      int rem = jid - ch*(BB*NFRAMES);
      b = rem / NFRAMES; f = rem - b*NFRAMES;
      x = (ch ? nR : nL) + (size_t)b*NSAMP;
      for (int n=j;n<256;n+=64){
        double a = (2.0*M_PI/256.0)*(double)n;
        int xi = f*NHOPF + n - 128;
        xi = xi < 0 ? -xi : xi;
        xi = xi >= NSAMP ? 2*(NSAMP-1)-xi : xi;
        float wnd = (float)(0.5 - 0.5*cos(a));
        frs[n] = x[xi]*wnd;
      }
    }
    __syncthreads();
    if (act){
      int ch = jid / (BB*NFRAMES);
      float* spec = ws + (ch ? OFF_SPECR : OFF_SPECL) + (size_t)(b*NFRAMES+f)*258;
      float re0=0.f, im0=0.f, re1=0.f, im1=0.f;
      int m0 = 0;
      #pragma unroll 4
      for (int n=0;n<256;n++){
        float fv = frs[n];
        int m1 = (m0 + ((n&3)<<6)) & 255;
        float2 t0 = tw[m0], t1 = tw[m1];
        re0 = fmaf(fv, t0.x, re0); im0 = fmaf(-fv, t0.y, im0);
        re1 = fmaf(fv, t1.x, re1); im1 = fmaf(-fv, t1.y, im1);
        m0 = (m0 + j) & 255;
      }
      float pq = frs[j] + frs[j+64] + frs[j+128] + frs[j+192];
      pq = (j & 1) ? -pq : pq;
      for (int o2=32;o2>0;o2>>=1) pq += __shfl_down(pq, o2, 64);
      spec[2*j]   = re0; spec[2*j+1]   = im0;
      spec[2*(j+64)] = re1; spec[2*(j+64)+1] = im1;
      if (j==0){ spec[256] = pq; spec[257] = 0.0f; }
    }
  }
}

// ---------------- fused post matmul + heads ----------------
__global__ __launch_bounds__(128) void k_posthead(const float* __restrict__ gout,
  const float* __restrict__ Wpo, const float* __restrict__ bpo,
  const float* __restrict__ WhL, const float* __restrict__ bhL,
  const float* __restrict__ WhR, const float* __restrict__ bhR,
  const float* __restrict__ Wam, const float* __restrict__ bam,
  const float* __restrict__ WnL, const float* __restrict__ bnL,
  const float* __restrict__ WnR, const float* __restrict__ bnR,
  float* __restrict__ harmL, float* __restrict__ harmR, float* __restrict__ amp,
  float* __restrict__ nmagL, float* __restrict__ nmagR){
  int row = blockIdx.x;
  int tid = threadIdx.x;
  __shared__ float gs[HID];
  __shared__ float post[MLPD];
  if (tid < HID) gs[tid] = gout[(size_t)row*HID + tid];
  __syncthreads();
  {
    const float* wp = Wpo + tid*HID;
    float acc = bpo[tid];
    #pragma unroll 8
    for (int i=0;i<HID;i++) acc = fmaf(gs[i], wp[i], acc);
    post[tid] = fmaxf(acc, 0.0f);
  }
  __syncthreads();
  #pragma unroll
  for (int rr=0;rr<3;rr++){
    int c = tid + rr*128;
    if (c >= 323) break;
    const float* W; const float* bb; float* o; int oc, ow; bool sp=false;
    if (c < 32)      { W=WhL; bb=bhL; o=harmL; oc=c;     ow=32; }
    else if (c < 64) { W=WhR; bb=bhR; o=harmR; oc=c-32;  ow=32; }
    else if (c == 64){ W=Wam; bb=bam; o=amp;   oc=0;     ow=1; sp=true; }
    else if (c < 194){ W=WnL; bb=bnL; o=nmagL; oc=c-65;  ow=129; }
    else             { W=WnR; bb=bnR; o=nmagR; oc=c-194; ow=129; }
    const float* wp = W + oc*MLPD;
    float acc = bb[oc];
    #pragma unroll 8
    for (int i=0;i<MLPD;i++) acc = fmaf(post[i], wp[i], acc);
    float v;
    if (sp) v = fmaxf(acc, 0.0f) + log1pf(expf(-fabsf(acc)));
    else    v = 1.0f/(1.0f+expf(-acc));
    o[(size_t)row*ow + oc] = v;
  }
}

// ---------------- mag filter + irfft + window (IN-PLACE, rotation twiddle) ----
// r15 post-mortem: tw[(k*t)&255] is a stride-k LDS read -> k%16==0 puts all
// 64 lanes on ONE bank (64-way conflict), even k 8-32-way. Replaced with a
// per-thread rotation recurrence (4 fmaf), mx[k] stays broadcast (no
// conflict). Drift over 127 rotations ~8e-6 abs -> ~1e-5 in sample.
__global__ __launch_bounds__(256) void k_istft(float* __restrict__ ws){
  int fr = blockIdx.x;
  int ch = blockIdx.y;
  int b = fr / NFRAMES, f = fr - b*NFRAMES;
  float* spec = ws + (ch ? OFF_SPECR : OFF_SPECL) + (size_t)fr*258;
  const float* nmag = ws + (ch ? OFF_NMAGR : OFF_NMAGL) + (size_t)b*TT*NBIN;
  int t = threadIdx.x;
  __shared__ float2 mx[NBIN];
  double a = (2.0*M_PI/256.0)*(double)t;
  float cz = (float)cos(a), sz = (float)sin(a);
  if (t < NBIN){
    float pos = ((float)f + 0.5f) * R_MAG - 0.5f;
    pos = fminf(fmaxf(pos, 0.0f), 499.0f);
    int i0 = (int)pos, i1 = min(i0+1, TT-1);
    float w = pos - (float)i0;
    float mg = nmag[i0*NBIN + t]*(1.0f-w) + nmag[i1*NBIN + t]*w;
    mx[t] = make_float2(spec[2*t]*mg, spec[2*t+1]*mg);
  }
  __syncthreads();                    // all spec reads done -> in-place safe
  float acc0 = mx[0].x + ((t&1) ? -mx[128].x : mx[128].x);
  float acc = 0.0f;
  float c = cz, s = sz;               // e^{i k theta_t}, k=1
  #pragma unroll 4
  for (int k=1;k<128;k++){
    float2 v = mx[k];                 // broadcast read, conflict-free
    acc = fmaf(v.x, c, acc);
    acc = fmaf(-v.y, s, acc);
    float ts_ = s*sz, tc_ = c*sz;
    float cn = fmaf(c, cz, -ts_);
    float sn = fmaf(s, cz,  tc_);
    c = cn; s = sn;
  }
  float y = (acc0 + 2.0f*acc) * (1.0f/256.0f);
  float win = 0.5f - 0.5f*cz;
  spec[t] = y*win;                    // overwrite own slot (258-stride frames)
}

// ---------------- final: harmonic synth + OLA gather ----------------
__global__ __launch_bounds__(256) void k_out(const float* __restrict__ f0,
    const float* __restrict__ ws, float* __restrict__ out){
  __shared__ float win2[256];
  __shared__ float c1s[BB*32];
  {
    int t = threadIdx.x;
    double a = (2.0*M_PI/256.0)*(double)t;
    float w = (float)(0.5 - 0.5*cos(a));
    win2[t] = w*w;
    if (t < BB*32) c1s[t] = ws[OFF_C1 + t];
  }
  __syncthreads();
  int idx = blockIdx.x*256 + threadIdx.x;
  if (idx >= BB*2*NSAMP) return;
  int m = idx % NSAMP;
  int bc = idx / NSAMP;
  int ch = bc & 1, b = bc >> 1;
  int i0,i1; float w,w1;
  up_coords(m,&i0,&i1,&w,&w1);
  const float* f0b = f0 + b*TT;
  float f0u = __fadd_rn(__fmul_rn(f0b[i0], w1), __fmul_rn(f0b[i1], w));
  const float* am = ws + OFF_AMP + b*TT;
  float oa = __fadd_rn(__fmul_rn(am[i0], w1), __fmul_rn(am[i1], w));
  const float* ha = ws + (ch ? OFF_HARMR : OFF_HARML) + (size_t)b*TT*NHARM;
  float tm = (float)m;
  float hsum = 0.0f;
  for (int k=1;k<=NHARM;k++){
    float instf = __fmul_rn(f0u, (float)k);
    if (instf < 21600.0f){
      float a0 = ha[i0*NHARM + (k-1)], a1 = ha[i1*NHARM + (k-1)];
      float ak = __fadd_rn(__fmul_rn(a0, w1), __fmul_rn(a1, w));
      float ph = __fmul_rn(c1s[b*32 + (k-1)], tm);
      double rev = (double)ph * 0.15915494309189535;
      double fr2 = rev - floor(rev);
      float rad = (float)((fr2 - (fr2 >= 0.5 ? 1.0 : 0.0)) * 6.283185307179586);
      float s = sinf(rad);
      hsum = __fadd_rn(hsum, __fmul_rn(ak, s));
    }
  }
  float harm = __fmul_rn(hsum, oa);
  int p = m + 128;
  int fhi = min(p >> 6, NFRAMES-1);
  int flo = max((p - 192) >> 6, 0);
  const float* frb = ws + (ch ? OFF_SPECR : OFF_SPECL) + (size_t)b*NFRAMES*258;
  float nacc = 0.0f, wsum = 0.0f;
  for (int f=flo; f<=fhi; f++){
    int n = p - f*NHOPF;
    nacc += frb[f*258 + n];
    wsum += win2[n];
  }
  float noise = nacc / fmaxf(wsum, 1e-11f);
  out[idx] = __fadd_rn(harm, noise);
}

extern "C" void kernel_launch(void* const* d_in, const int* in_sizes, int n_in,
                              void* d_out, int out_size, void* d_ws, size_t ws_size,
                              hipStream_t stream){
  const float* f0  = (const float*)d_in[0];
  const float* ldb = (const float*)d_in[1];
  const float* vel = (const float*)d_in[2];
  const float* nL  = (const float*)d_in[3];
  const float* nR  = (const float*)d_in[4];
  const float* Wp1 = (const float*)d_in[5];
  const float* bp1 = (const float*)d_in[6];
  const float* Wp2 = (const float*)d_in[7];
  const float* bp2 = (const float*)d_in[8];
  const float* Wih = (const float*)d_in[9];
  const float* Whh = (const float*)d_in[10];
  const float* bih = (const float*)d_in[11];
  const float* bhh = (const float*)d_in[12];
  const float* Wpo = (const float*)d_in[13];
  const float* bpo = (const float*)d_in[14];
  const float* WhL = (const float*)d_in[15];
  const float* bhL = (const float*)d_in[16];
  const float* WhR = (const float*)d_in[17];
  const float* bhR = (const float*)d_in[18];
  const float* Wam = (const float*)d_in[19];
  const float* bam = (const float*)d_in[20];
  const float* WnL = (const float*)d_in[21];
  const float* bnL = (const float*)d_in[22];
  const float* WnR = (const float*)d_in[23];
  const float* bnR = (const float*)d_in[24];
  float* ws = (float*)d_ws;
  float* out = (float*)d_out;

  k_encmm<<<BB*TT, 128, 0, stream>>>(f0, ldb, vel, Wp1, bp1, ws+OFF_H1);
  k_mm2gi<<<BB*TT, 192, 0, stream>>>(ws+OFF_H1, Wp2, bp2, Wih, bih, ws+OFF_GI);
  k_mid<<<MID_BLOCKS, 384, 0, stream>>>(ws+OFF_GI, Whh, bhh, ws+OFF_GOUT, f0, nL, nR, ws);
  k_posthead<<<BB*TT, 128, 0, stream>>>(ws+OFF_GOUT, Wpo, bpo,
      WhL,bhL, WhR,bhR, Wam,bam, WnL,bnL, WnR,bnR,
      ws+OFF_HARML, ws+OFF_HARMR, ws+OFF_AMP, ws+OFF_NMAGL, ws+OFF_NMAGR);
  dim3 gs(BB*NFRAMES, 2);
  k_istft<<<gs, 256, 0, stream>>>(ws);
  k_out<<<(BB*2*NSAMP+255)/256, 256, 0, stream>>>(f0, ws, out);
}

// Round 17
// 433.096 us; speedup vs baseline: 1.3736x; 1.0552x over previous
//
#include <hip/hip_runtime.h>
#include <math.h>

#ifndef M_PI
#define M_PI 3.14159265358979323846
#endif

#define BB 4
#define TT 500
#define NSAMP 120000
#define NHARM 32
#define NFFT 256
#define NBIN 129
#define NHOPF 64
#define NFRAMES 1876
#define HID 64
#define MLPD 128
#define FEATD 88

#define R_MAG ((float)(500.0/1876.0))
#define R_UP_F ((float)(500.0/120000.0))

typedef float v2f __attribute__((ext_vector_type(2)));

// ---- workspace layout (float offsets) ----
#define OFF_HARML 0
#define OFF_HARMR 64000
#define OFF_AMP   128000
#define OFF_NMAGL 130000
#define OFF_NMAGR 388000
#define OFF_C1    646000
#define OFF_H1    646128
#define OFF_GI    (OFF_H1+256000)
#define OFF_GOUT  (OFF_GI+384000)
#define OFF_SPECL (OFF_GOUT+128000)
#define OFF_SPECR (OFF_SPECL+4*NFRAMES*258)
/* end = 5286160 floats = 21.1 MB */

// f32 upsample position/interp chain, bit-exact to numpy float32 elementwise
__device__ __forceinline__ void up_coords(int m, int* i0, int* i1, float* w, float* w1){
  float pos = __fadd_rn(__fmul_rn(__fadd_rn((float)m, 0.5f), R_UP_F), -0.5f);
  pos = fminf(fmaxf(pos, 0.0f), 499.0f);
  int a = (int)pos;
  *i0 = a; *i1 = min(a+1, TT-1);
  float ww = __fsub_rn(pos, (float)a);
  *w = ww; *w1 = __fsub_rn(1.0f, ww);
}
__device__ __forceinline__ float f0_up_elem(const float* __restrict__ f0s, int m){
  int i0,i1; float w,w1;
  up_coords(m,&i0,&i1,&w,&w1);
  return __fadd_rn(__fmul_rn(f0s[i0], w1), __fmul_rn(f0s[i1], w));
}

// ---------------- fused front: enc + pre1 + pre2 + gi (one launch) ----------------
// Bit-identical chains to the previous k_encmm/k_mm2gi pair; feat/h1/h2 stay
// in LDS (saves the H1 global round-trip + one launch).
__global__ __launch_bounds__(192) void k_front(const float* __restrict__ f0,
    const float* __restrict__ ldb, const float* __restrict__ vel,
    const float* __restrict__ Wp1, const float* __restrict__ bp1,
    const float* __restrict__ Wp2, const float* __restrict__ bp2,
    const float* __restrict__ Wih, const float* __restrict__ bih,
    float* __restrict__ gi){
  int row = blockIdx.x;
  int b = row / TT;
  int tid = threadIdx.x;
  __shared__ float feat[FEATD];
  __shared__ float h1s[MLPD];
  __shared__ float h2s[MLPD];
  if (tid < FEATD){
    float f = f0[row];
    float gate = (f > 0.0f) ? 1.0f : 0.0f;
    float fs = fmaxf(f, 20.0f);
    float fn = (logf(fs) - (float)2.995732273553991) / (float)5.5214609178622464;
    fn = fminf(fmaxf(fn, 0.0f), 1.0f);
    float ln = fminf(fmaxf((ldb[row] + 80.0f) / 80.0f, 0.0f), 1.0f);
    float vn = fminf(fmaxf(vel[b] / 7.0f, 0.0f), 1.0f);
    float norm; int i; float g2 = 1.0f;
    if (tid < 64){ i = (tid>>1) + 1; norm = fn; g2 = gate; }
    else if (tid < 80){ i = ((tid-64)>>1) + 1; norm = ln; }
    else { i = ((tid-80)>>1) + 1; norm = vn; }
    float ang = (float)M_PI * (float)i * norm;
    feat[tid] = ((tid & 1) ? cosf(ang) : sinf(ang)) * g2;
  }
  __syncthreads();
  if (tid < MLPD){
    const float* wp = Wp1 + tid*FEATD;
    float acc = bp1[tid];
    #pragma unroll 8
    for (int i=0;i<FEATD;i++) acc = fmaf(feat[i], wp[i], acc);
    h1s[tid] = fmaxf(acc, 0.0f);
  }
  __syncthreads();
  if (tid < MLPD){
    const float* wp = Wp2 + tid*MLPD;
    float acc = bp2[tid];
    #pragma unroll 8
    for (int i=0;i<MLPD;i++) acc = fmaf(h1s[i], wp[i], acc);
    h2s[tid] = fmaxf(acc, 0.0f);
  }
  __syncthreads();
  {
    const float* wp = Wih + tid*MLPD;
    float acc = bih[tid];
    #pragma unroll 8
    for (int i=0;i<MLPD;i++) acc = fmaf(h2s[i], wp[i], acc);
    gi[(size_t)row*192 + tid] = acc;
  }
}

// numpy-exact pairwise block sum (leaf of the depth-10 perfect tree)
__device__ float np_block_sum(const float* __restrict__ f0s, int off, int n, float kf){
  float r[8];
  #pragma unroll
  for (int j=0;j<8;j++) r[j] = __fmul_rn(f0_up_elem(f0s, off+j), kf);
  int lim = n - (n & 7);
  int i = 8;
  for (; i<lim; i+=8){
    #pragma unroll
    for (int j=0;j<8;j++)
      r[j] = __fadd_rn(r[j], __fmul_rn(f0_up_elem(f0s, off+i+j), kf));
  }
  float res = __fadd_rn(__fadd_rn(__fadd_rn(r[0],r[1]), __fadd_rn(r[2],r[3])),
                        __fadd_rn(__fadd_rn(r[4],r[5]), __fadd_rn(r[6],r[7])));
  for (; i<n; i++)
    res = __fadd_rn(res, __fmul_rn(f0_up_elem(f0s, off+i), kf));
  return res;
}

// ---------------- fused mid: GRU + STFT + meanf0 ----------------
#define MID_GRU   BB
#define MID_MF    (MID_GRU + BB*32)
#define STFT_JOBS (2*BB*NFRAMES)
#define MID_STFT_BLOCKS ((STFT_JOBS+5)/6)
#define MID_BLOCKS (MID_MF + MID_STFT_BLOCKS)

#define RL(x,l) __uint_as_float(__builtin_amdgcn_readlane(__float_as_uint(x), (l)))

#define CH  25
#define NCH 20

// fast activations (v_exp_f32-based, ~2ulp). VALIDATED r14/r15: absmax stayed
// EXACTLY 0.1135254 (max error lives in the phase path, not the GRU).
__device__ __forceinline__ float fsig(float x){
  return __fdividef(1.0f, 1.0f + __expf(-x));
}
__device__ __forceinline__ float ftanh(float x){
  return fmaf(-2.0f, __fdividef(1.0f, 1.0f + __expf(2.0f*x)), 1.0f);
}

// r16 post-mortem: k_mid had NO waves_per_eu attribute -> allocator budget
// 112 VGPR < 192 weights -> remat-from-L2 every iteration (the r5-r9 bug,
// reintroduced by the k_mid fusion). (2,2): 6 waves/block needs min 2/EU;
// budget 256 VGPR fits 192 weights + overhead. LDS (54.8KB) already caps
// occupancy at 2 blocks/CU, so no loss for the stft/meanf0 sections.
__global__
__attribute__((amdgpu_flat_work_group_size(384,384)))
__attribute__((amdgpu_waves_per_eu(2,2)))
void k_mid(
    const float* __restrict__ gi, const float* __restrict__ Whh,
    const float* __restrict__ bhh, float* __restrict__ gout,
    const float* __restrict__ f0, const float* __restrict__ nL,
    const float* __restrict__ nR, float* __restrict__ ws){
  // GRU LDS: gibuf 2*4800 + hist 4096 = 13696 floats (54.8KB)
  __shared__ __align__(16) float sh[13696];
  int blk = blockIdx.x;
  int tid = threadIdx.x;

  if (blk < MID_GRU){
    // ---- GRU (r13 structure + fast act + PACKED dot): consumer wave
    // free-runs from LDS-staged gi; 3 producer waves double-buffer chunks.
    // Dot uses v_pk_fma_f32 (v2f pairs): 192 fmaf -> 96 pk_fma. Pair
    // partition only changes accumulation order (r11/r13: order-insensitive).
    float* gibuf = sh;            // [2][4800]
    float* hist  = sh + 9600;     // [64][64]
    int b = blk;
    int j = tid & 63;
    v2f wr2[32], wz2[32], wn2[32];
    float br=0.f, bz=0.f, bn=0.f;
    if (tid < 64){
      #pragma unroll
      for (int i=0;i<16;i++){
        float4 a = *(const float4*)(Whh + (size_t)(j)*64     + i*4);
        float4 c = *(const float4*)(Whh + (size_t)(64+j)*64  + i*4);
        float4 d = *(const float4*)(Whh + (size_t)(128+j)*64 + i*4);
        wr2[2*i] = (v2f){a.x, a.y}; wr2[2*i+1] = (v2f){a.z, a.w};
        wz2[2*i] = (v2f){c.x, c.y}; wz2[2*i+1] = (v2f){c.z, c.w};
        wn2[2*i] = (v2f){d.x, d.y}; wn2[2*i+1] = (v2f){d.z, d.w};
      }
      br = bhh[j]; bz = bhh[64+j]; bn = bhh[128+j];
    }
    const float* gbase = gi + (size_t)b*TT*192;
    // stage chunk 0
    if (tid >= 64){
      int pt = tid - 64;
      for (int idx = pt; idx < CH*48; idx += 192){
        float4 v = *(const float4*)(gbase + idx*4);
        *(float4*)&gibuf[idx*4] = v;
      }
    }
    __syncthreads();
    float hreg = 0.0f;
    float* op = gout + (size_t)b*TT*64;
    for (int c=0; c<NCH; c++){
      if (tid >= 64){
        if (c+1 < NCH){
          int pt = tid - 64;
          const float* src = gbase + (size_t)(c+1)*CH*192;
          float* dst = &gibuf[((c+1)&1)*4800];
          for (int idx = pt; idx < CH*48; idx += 192){
            float4 v = *(const float4*)(src + idx*4);
            *(float4*)&dst[idx*4] = v;
          }
        }
      } else {
        const float* gch = &gibuf[(c&1)*4800];
        for (int tt=0; tt<CH; tt++){
          int t = c*CH + tt;
          float gr0 = gch[tt*192 + j];
          float gz0 = gch[tt*192 + 64 + j];
          float gn0 = gch[tt*192 + 128 + j];
          v2f AR0={0.f,0.f}, AR1={0.f,0.f};
          v2f AZ0={0.f,0.f}, AZ1={0.f,0.f};
          v2f AN0={0.f,0.f}, AN1={0.f,0.f};
          #pragma unroll
          for (int i=0;i<16;i++){
            v2f hA, hB;
            hA.x = RL(hreg, 2*i);    hA.y = RL(hreg, 2*i+1);
            hB.x = RL(hreg, 32+2*i); hB.y = RL(hreg, 33+2*i);
            AR0 = __builtin_elementwise_fma(wr2[i],    hA, AR0);
            AR1 = __builtin_elementwise_fma(wr2[16+i], hB, AR1);
            AZ0 = __builtin_elementwise_fma(wz2[i],    hA, AZ0);
            AZ1 = __builtin_elementwise_fma(wz2[16+i], hB, AZ1);
            AN0 = __builtin_elementwise_fma(wn2[i],    hA, AN0);
            AN1 = __builtin_elementwise_fma(wn2[16+i], hB, AN1);
          }
          float ar = __fadd_rn(__fadd_rn(AR0.x,AR0.y), __fadd_rn(AR1.x,AR1.y));
          float az = __fadd_rn(__fadd_rn(AZ0.x,AZ0.y), __fadd_rn(AZ1.x,AZ1.y));
          float an = __fadd_rn(__fadd_rn(AN0.x,AN0.y), __fadd_rn(AN1.x,AN1.y));
          float r = fsig(gr0 + ar + br);
          float z = fsig(gz0 + az + bz);
          float n = ftanh(gn0 + r*(an+bn));
          hreg = (1.0f - z)*n + z*hreg;
          int th = t & 63;
          hist[th*64 + j] = hreg;
          if (th == 63 || t == TT-1){
            int base_t = t - th;
            int per = th + 1;
            int nb = per >> 2;
            float* dst2 = op + base_t*64 + j*per;
            for (int q=0;q<nb;q++){
              float4 v = *(float4*)&hist[j*per + q*4];
              *(float4*)&dst2[q*4] = v;
            }
          }
        }
      }
      __syncthreads();
    }
  } else if (blk < MID_MF){
    // ---- meanf0 (bit-exact numpy pairwise tree)
    int bk = blk - MID_GRU;
    int b = bk >> 5, k = bk & 31;
    float kf = (float)(k+1);
    float* f0s = sh;
    float* red = sh + 512;
    for (int i=tid;i<TT;i+=384) f0s[i] = f0[b*TT+i];
    __syncthreads();
    if (tid < 256){
      float lv[4];
      #pragma unroll
      for (int q=0;q<4;q++){
        int leafIdx = tid*4 + q;
        int off = 0, n = NSAMP;
        #pragma unroll
        for (int lvl=9; lvl>=0; --lvl){
          int n2 = (n>>1); n2 -= (n2 & 7);
          if ((leafIdx >> lvl) & 1){ off += n2; n -= n2; } else { n = n2; }
        }
        lv[q] = np_block_sum(f0s, off, n, kf);
      }
      red[tid] = __fadd_rn(__fadd_rn(lv[0],lv[1]), __fadd_rn(lv[2],lv[3]));
    }
    __syncthreads();
    for (int cnt=256; cnt>1; cnt>>=1){
      int half = cnt>>1;
      float v = 0.0f;
      if (tid < half) v = __fadd_rn(red[2*tid], red[2*tid+1]);
      __syncthreads();
      if (tid < half) red[tid] = v;
      __syncthreads();
    }
    if (tid==0){
      float mf = __fdiv_rn(red[0], 120000.0f);
      float c1 = __fmul_rn((float)(2.0*M_PI/48000.0), mf);
      ws[OFF_C1 + b*32 + k] = c1;
    }
  } else {
    // ---- STFT: 6 frames per block (one wave each), shared twiddle table
    int base = (blk - MID_MF)*6;
    int sub = tid >> 6;
    int j = tid & 63;
    float2* tw = (float2*)sh;
    float* frs = sh + 512 + sub*256;
    if (tid < 256){
      double a = (2.0*M_PI/256.0)*(double)tid;
      tw[tid] = make_float2((float)cos(a), (float)sin(a));
    }
    int jid = base + sub;
    bool act = jid < STFT_JOBS;
    int b=0, f=0; const float* x = nL;
    if (act){
      int ch = jid / (BB*NFRAMES);
      int rem = jid - ch*(BB*NFRAMES);
      b = rem / NFRAMES; f = rem - b*NFRAMES;
      x = (ch ? nR : nL) + (size_t)b*NSAMP;
      for (int n=j;n<256;n+=64){
        double a = (2.0*M_PI/256.0)*(double)n;
        int xi = f*NHOPF + n - 128;
        xi = xi < 0 ? -xi : xi;
        xi = xi >= NSAMP ? 2*(NSAMP-1)-xi : xi;
        float wnd = (float)(0.5 - 0.5*cos(a));
        frs[n] = x[xi]*wnd;
      }
    }
    __syncthreads();
    if (act){
      int ch = jid / (BB*NFRAMES);
      float* spec = ws + (ch ? OFF_SPECR : OFF_SPECL) + (size_t)(b*NFRAMES+f)*258;
      float re0=0.f, im0=0.f, re1=0.f, im1=0.f;
      int m0 = 0;
      #pragma unroll 4
      for (int n=0;n<256;n++){
        float fv = frs[n];
        int m1 = (m0 + ((n&3)<<6)) & 255;
        float2 t0 = tw[m0], t1 = tw[m1];
        re0 = fmaf(fv, t0.x, re0); im0 = fmaf(-fv, t0.y, im0);
        re1 = fmaf(fv, t1.x, re1); im1 = fmaf(-fv, t1.y, im1);
        m0 = (m0 + j) & 255;
      }
      float pq = frs[j] + frs[j+64] + frs[j+128] + frs[j+192];
      pq = (j & 1) ? -pq : pq;
      for (int o2=32;o2>0;o2>>=1) pq += __shfl_down(pq, o2, 64);
      spec[2*j]   = re0; spec[2*j+1]   = im0;
      spec[2*(j+64)] = re1; spec[2*(j+64)+1] = im1;
      if (j==0){ spec[256] = pq; spec[257] = 0.0f; }
    }
  }
}

// ---------------- fused post matmul + heads ----------------
__global__ __launch_bounds__(128) void k_posthead(const float* __restrict__ gout,
  const float* __restrict__ Wpo, const float* __restrict__ bpo,
  const float* __restrict__ WhL, const float* __restrict__ bhL,
  const float* __restrict__ WhR, const float* __restrict__ bhR,
  const float* __restrict__ Wam, const float* __restrict__ bam,
  const float* __restrict__ WnL, const float* __restrict__ bnL,
  const float* __restrict__ WnR, const float* __restrict__ bnR,
  float* __restrict__ harmL, float* __restrict__ harmR, float* __restrict__ amp,
  float* __restrict__ nmagL, float* __restrict__ nmagR){
  int row = blockIdx.x;
  int tid = threadIdx.x;
  __shared__ float gs[HID];
  __shared__ float post[MLPD];
  if (tid < HID) gs[tid] = gout[(size_t)row*HID + tid];
  __syncthreads();
  {
    const float* wp = Wpo + tid*HID;
    float acc = bpo[tid];
    #pragma unroll 8
    for (int i=0;i<HID;i++) acc = fmaf(gs[i], wp[i], acc);
    post[tid] = fmaxf(acc, 0.0f);
  }
  __syncthreads();
  #pragma unroll
  for (int rr=0;rr<3;rr++){
    int c = tid + rr*128;
    if (c >= 323) break;
    const float* W; const float* bb; float* o; int oc, ow; bool sp=false;
    if (c < 32)      { W=WhL; bb=bhL; o=harmL; oc=c;     ow=32; }
    else if (c < 64) { W=WhR; bb=bhR; o=harmR; oc=c-32;  ow=32; }
    else if (c == 64){ W=Wam; bb=bam; o=amp;   oc=0;     ow=1; sp=true; }
    else if (c < 194){ W=WnL; bb=bnL; o=nmagL; oc=c-65;  ow=129; }
    else             { W=WnR; bb=bnR; o=nmagR; oc=c-194; ow=129; }
    const float* wp = W + oc*MLPD;
    float acc = bb[oc];
    #pragma unroll 8
    for (int i=0;i<MLPD;i++) acc = fmaf(post[i], wp[i], acc);
    float v;
    if (sp) v = fmaxf(acc, 0.0f) + log1pf(expf(-fabsf(acc)));
    else    v = 1.0f/(1.0f+expf(-acc));
    o[(size_t)row*ow + oc] = v;
  }
}

// ---------------- mag filter + irfft + window (IN-PLACE, rotation twiddle) ----
__global__ __launch_bounds__(256) void k_istft(float* __restrict__ ws){
  int fr = blockIdx.x;
  int ch = blockIdx.y;
  int b = fr / NFRAMES, f = fr - b*NFRAMES;
  float* spec = ws + (ch ? OFF_SPECR : OFF_SPECL) + (size_t)fr*258;
  const float* nmag = ws + (ch ? OFF_NMAGR : OFF_NMAGL) + (size_t)b*TT*NBIN;
  int t = threadIdx.x;
  __shared__ float2 mx[NBIN];
  double a = (2.0*M_PI/256.0)*(double)t;
  float cz = (float)cos(a), sz = (float)sin(a);
  if (t < NBIN){
    float pos = ((float)f + 0.5f) * R_MAG - 0.5f;
    pos = fminf(fmaxf(pos, 0.0f), 499.0f);
    int i0 = (int)pos, i1 = min(i0+1, TT-1);
    float w = pos - (float)i0;
    float mg = nmag[i0*NBIN + t]*(1.0f-w) + nmag[i1*NBIN + t]*w;
    mx[t] = make_float2(spec[2*t]*mg, spec[2*t+1]*mg);
  }
  __syncthreads();                    // all spec reads done -> in-place safe
  float acc0 = mx[0].x + ((t&1) ? -mx[128].x : mx[128].x);
  float acc = 0.0f;
  float c = cz, s = sz;               // e^{i k theta_t}, k=1
  #pragma unroll 4
  for (int k=1;k<128;k++){
    float2 v = mx[k];                 // broadcast read, conflict-free
    acc = fmaf(v.x, c, acc);
    acc = fmaf(-v.y, s, acc);
    float ts_ = s*sz, tc_ = c*sz;
    float cn = fmaf(c, cz, -ts_);
    float sn = fmaf(s, cz,  tc_);
    c = cn; s = sn;
  }
  float y = (acc0 + 2.0f*acc) * (1.0f/256.0f);
  float win = 0.5f - 0.5f*cz;
  spec[t] = y*win;                    // overwrite own slot (258-stride frames)
}

// ---------------- final: harmonic synth + OLA gather ----------------
__global__ __launch_bounds__(256) void k_out(const float* __restrict__ f0,
    const float* __restrict__ ws, float* __restrict__ out){
  __shared__ float win2[256];
  __shared__ float c1s[BB*32];
  {
    int t = threadIdx.x;
    double a = (2.0*M_PI/256.0)*(double)t;
    float w = (float)(0.5 - 0.5*cos(a));
    win2[t] = w*w;
    if (t < BB*32) c1s[t] = ws[OFF_C1 + t];
  }
  __syncthreads();
  int idx = blockIdx.x*256 + threadIdx.x;
  if (idx >= BB*2*NSAMP) return;
  int m = idx % NSAMP;
  int bc = idx / NSAMP;
  int ch = bc & 1, b = bc >> 1;
  int i0,i1; float w,w1;
  up_coords(m,&i0,&i1,&w,&w1);
  const float* f0b = f0 + b*TT;
  float f0u = __fadd_rn(__fmul_rn(f0b[i0], w1), __fmul_rn(f0b[i1], w));
  const float* am = ws + OFF_AMP + b*TT;
  float oa = __fadd_rn(__fmul_rn(am[i0], w1), __fmul_rn(am[i1], w));
  const float* ha = ws + (ch ? OFF_HARMR : OFF_HARML) + (size_t)b*TT*NHARM;
  float tm = (float)m;
  float hsum = 0.0f;
  for (int k=1;k<=NHARM;k++){
    float instf = __fmul_rn(f0u, (float)k);
    if (instf < 21600.0f){
      float a0 = ha[i0*NHARM + (k-1)], a1 = ha[i1*NHARM + (k-1)];
      float ak = __fadd_rn(__fmul_rn(a0, w1), __fmul_rn(a1, w));
      float ph = __fmul_rn(c1s[b*32 + (k-1)], tm);
      double rev = (double)ph * 0.15915494309189535;
      double fr2 = rev - floor(rev);
      float rad = (float)((fr2 - (fr2 >= 0.5 ? 1.0 : 0.0)) * 6.283185307179586);
      float s = sinf(rad);
      hsum = __fadd_rn(hsum, __fmul_rn(ak, s));
    }
  }
  float harm = __fmul_rn(hsum, oa);
  int p = m + 128;
  int fhi = min(p >> 6, NFRAMES-1);
  int flo = max((p - 192) >> 6, 0);
  const float* frb = ws + (ch ? OFF_SPECR : OFF_SPECL) + (size_t)b*NFRAMES*258;
  float nacc = 0.0f, wsum = 0.0f;
  for (int f=flo; f<=fhi; f++){
    int n = p - f*NHOPF;
    nacc += frb[f*258 + n];
    wsum += win2[n];
  }
  float noise = nacc / fmaxf(wsum, 1e-11f);
  out[idx] = __fadd_rn(harm, noise);
}

extern "C" void kernel_launch(void* const* d_in, const int* in_sizes, int n_in,
                              void* d_out, int out_size, void* d_ws, size_t ws_size,
                              hipStream_t stream){
  const float* f0  = (const float*)d_in[0];
  const float* ldb = (const float*)d_in[1];
  const float* vel = (const float*)d_in[2];
  const float* nL  = (const float*)d_in[3];
  const float* nR  = (const float*)d_in[4];
  const float* Wp1 = (const float*)d_in[5];
  const float* bp1 = (const float*)d_in[6];
  const float* Wp2 = (const float*)d_in[7];
  const float* bp2 = (const float*)d_in[8];
  const float* Wih = (const float*)d_in[9];
  const float* Whh = (const float*)d_in[10];
  const float* bih = (const float*)d_in[11];
  const float* bhh = (const float*)d_in[12];
  const float* Wpo = (const float*)d_in[13];
  const float* bpo = (const float*)d_in[14];
  const float* WhL = (const float*)d_in[15];
  const float* bhL = (const float*)d_in[16];
  const float* WhR = (const float*)d_in[17];
  const float* bhR = (const float*)d_in[18];
  const float* Wam = (const float*)d_in[19];
  const float* bam = (const float*)d_in[20];
  const float* WnL = (const float*)d_in[21];
  const float* bnL = (const float*)d_in[22];
  const float* WnR = (const float*)d_in[23];
  const float* bnR = (const float*)d_in[24];
  float* ws = (float*)d_ws;
  float* out = (float*)d_out;

  k_front<<<BB*TT, 192, 0, stream>>>(f0, ldb, vel, Wp1, bp1, Wp2, bp2, Wih, bih, ws+OFF_GI);
  k_mid<<<MID_BLOCKS, 384, 0, stream>>>(ws+OFF_GI, Whh, bhh, ws+OFF_GOUT, f0, nL, nR, ws);
  k_posthead<<<BB*TT, 128, 0, stream>>>(ws+OFF_GOUT, Wpo, bpo,
      WhL,bhL, WhR,bhR, Wam,bam, WnL,bnL, WnR,bnR,
      ws+OFF_HARML, ws+OFF_HARMR, ws+OFF_AMP, ws+OFF_NMAGL, ws+OFF_NMAGR);
  dim3 gs(BB*NFRAMES, 2);
  k_istft<<<gs, 256, 0, stream>>>(ws);
  k_out<<<(BB*2*NSAMP+255)/256, 256, 0, stream>>>(f0, ws, out);
}

// Round 18
// 411.091 us; speedup vs baseline: 1.4472x; 1.0535x over previous
//
#include <hip/hip_runtime.h>
#include <math.h>

#ifndef M_PI
#define M_PI 3.14159265358979323846
#endif

#define BB 4
#define TT 500
#define NSAMP 120000
#define NHARM 32
#define NFFT 256
#define NBIN 129
#define NHOPF 64
#define NFRAMES 1876
#define HID 64
#define MLPD 128
#define FEATD 88

#define R_MAG ((float)(500.0/1876.0))
#define R_UP_F ((float)(500.0/120000.0))

typedef float v2f __attribute__((ext_vector_type(2)));

// ---- workspace layout (float offsets) ----
#define OFF_HARML 0
#define OFF_HARMR 64000
#define OFF_AMP   128000
#define OFF_NMAGL 130000
#define OFF_NMAGR 388000
#define OFF_C1    646000
#define OFF_H1    646128
#define OFF_GI    (OFF_H1+256000)
#define OFF_GOUT  (OFF_GI+384000)
#define OFF_SPECL (OFF_GOUT+128000)
#define OFF_SPECR (OFF_SPECL+4*NFRAMES*258)
#define WS_END0   (OFF_SPECR+4*NFRAMES*258)     /* 5286160 */
/* transposed weights (k_prep) */
#define OFF_WT1   WS_END0                        /* [88][128]  11264 */
#define OFF_WT2   (OFF_WT1+11264)                /* [128][128] 16384 */
#define OFF_WTIH  (OFF_WT2+16384)                /* [128][192] 24576 */
#define OFF_WTPO  (OFF_WTIH+24576)               /* [64][128]   8192 */
#define OFF_WTH   (OFF_WTPO+8192)                /* [128][323] 41344 */
/* end = 5387920 floats = 21.6 MB */
#define PREP_TOT (11264+16384+24576+8192+41344)

// f32 upsample position/interp chain, bit-exact to numpy float32 elementwise
__device__ __forceinline__ void up_coords(int m, int* i0, int* i1, float* w, float* w1){
  float pos = __fadd_rn(__fmul_rn(__fadd_rn((float)m, 0.5f), R_UP_F), -0.5f);
  pos = fminf(fmaxf(pos, 0.0f), 499.0f);
  int a = (int)pos;
  *i0 = a; *i1 = min(a+1, TT-1);
  float ww = __fsub_rn(pos, (float)a);
  *w = ww; *w1 = __fsub_rn(1.0f, ww);
}
__device__ __forceinline__ float f0_up_elem(const float* __restrict__ f0s, int m){
  int i0,i1; float w,w1;
  up_coords(m,&i0,&i1,&w,&w1);
  return __fadd_rn(__fmul_rn(f0s[i0], w1), __fmul_rn(f0s[i1], w));
}

// ---------------- one-time weight transpose to [in][out] ----------------
__global__ __launch_bounds__(256) void k_prep(const float* __restrict__ Wp1,
    const float* __restrict__ Wp2, const float* __restrict__ Wih,
    const float* __restrict__ Wpo, const float* __restrict__ WhL,
    const float* __restrict__ WhR, const float* __restrict__ Wam,
    const float* __restrict__ WnL, const float* __restrict__ WnR,
    float* __restrict__ ws){
  int idx = blockIdx.x*256 + threadIdx.x;
  if (idx >= PREP_TOT) return;
  if (idx < 11264){ int i = idx >> 7, c = idx & 127; ws[OFF_WT1 + idx] = Wp1[c*FEATD + i]; return; }
  idx -= 11264;
  if (idx < 16384){ int i = idx >> 7, c = idx & 127; ws[OFF_WT2 + idx] = Wp2[c*MLPD + i]; return; }
  idx -= 16384;
  if (idx < 24576){ int i = idx / 192, c = idx - i*192; ws[OFF_WTIH + idx] = Wih[c*MLPD + i]; return; }
  idx -= 24576;
  if (idx < 8192){ int i = idx >> 7, c = idx & 127; ws[OFF_WTPO + idx] = Wpo[c*HID + i]; return; }
  idx -= 8192;
  { int i = idx / 323, c = idx - i*323;
    float v;
    if (c < 32)       v = WhL[c*MLPD + i];
    else if (c < 64)  v = WhR[(c-32)*MLPD + i];
    else if (c == 64) v = Wam[i];
    else if (c < 194) v = WnL[(c-65)*MLPD + i];
    else              v = WnR[(c-194)*MLPD + i];
    ws[OFF_WTH + idx] = v; }
}

// ---------------- fused front: enc+pre1+pre2+gi, 10 rows/block ----------------
// Coalesced transposed weights (1x stream per block instead of 1x per row);
// all LDS activation reads are wave-uniform (broadcast). Each output keeps
// the sequential single-acc i-chain -> bit-identical to r17.
#define ROWS_F 10
__global__ __launch_bounds__(256) void k_front(const float* __restrict__ f0,
    const float* __restrict__ ldb, const float* __restrict__ vel,
    const float* __restrict__ bp1, const float* __restrict__ bp2,
    const float* __restrict__ bih, float* __restrict__ ws){
  int r0 = blockIdx.x * ROWS_F;
  int tid = threadIdx.x;
  __shared__ float norms[ROWS_F][4];
  __shared__ float feat[ROWS_F][FEATD];
  __shared__ float h1[ROWS_F][MLPD];
  __shared__ float h2[ROWS_F][MLPD];
  if (tid < ROWS_F){
    int row = r0 + tid; int b = row / TT;
    float f = f0[row];
    norms[tid][3] = (f > 0.0f) ? 1.0f : 0.0f;
    float fs = fmaxf(f, 20.0f);
    float fn = (logf(fs) - (float)2.995732273553991) / (float)5.5214609178622464;
    norms[tid][0] = fminf(fmaxf(fn, 0.0f), 1.0f);
    norms[tid][1] = fminf(fmaxf((ldb[row] + 80.0f) / 80.0f, 0.0f), 1.0f);
    norms[tid][2] = fminf(fmaxf(vel[b] / 7.0f, 0.0f), 1.0f);
  }
  __syncthreads();
  for (int idx = tid; idx < ROWS_F*FEATD; idx += 256){
    int r = idx / FEATD, e = idx - r*FEATD;
    float norm, g2 = 1.0f; int i;
    if (e < 64){ i = (e>>1)+1; norm = norms[r][0]; g2 = norms[r][3]; }
    else if (e < 80){ i = ((e-64)>>1)+1; norm = norms[r][1]; }
    else { i = ((e-80)>>1)+1; norm = norms[r][2]; }
    float ang = (float)M_PI * (float)i * norm;
    feat[r][e] = ((e & 1) ? cosf(ang) : sinf(ang)) * g2;
  }
  __syncthreads();
  { // pre1: c=tid&127, row-group tid>>7 handles 5 rows
    int c = tid & 127, rg = tid >> 7;
    const float* wt = ws + OFF_WT1;
    float acc[5];
    #pragma unroll
    for (int q=0;q<5;q++) acc[q] = bp1[c];
    for (int i=0;i<FEATD;i++){
      float w = wt[i*128 + c];
      #pragma unroll
      for (int q=0;q<5;q++) acc[q] = fmaf(feat[rg*5+q][i], w, acc[q]);
    }
    #pragma unroll
    for (int q=0;q<5;q++) h1[rg*5+q][c] = fmaxf(acc[q], 0.0f);
  }
  __syncthreads();
  { // pre2
    int c = tid & 127, rg = tid >> 7;
    const float* wt = ws + OFF_WT2;
    float acc[5];
    #pragma unroll
    for (int q=0;q<5;q++) acc[q] = bp2[c];
    for (int i=0;i<MLPD;i++){
      float w = wt[i*128 + c];
      #pragma unroll
      for (int q=0;q<5;q++) acc[q] = fmaf(h1[rg*5+q][i], w, acc[q]);
    }
    #pragma unroll
    for (int q=0;q<5;q++) h2[rg*5+q][c] = fmaxf(acc[q], 0.0f);
  }
  __syncthreads();
  if (tid < 192){ // gi: one col per thread, all 10 rows
    const float* wt = ws + OFF_WTIH;
    float* gi = ws + OFF_GI;
    float acc[ROWS_F];
    #pragma unroll
    for (int r=0;r<ROWS_F;r++) acc[r] = bih[tid];
    for (int i=0;i<MLPD;i++){
      float w = wt[i*192 + tid];
      #pragma unroll
      for (int r=0;r<ROWS_F;r++) acc[r] = fmaf(h2[r][i], w, acc[r]);
    }
    #pragma unroll
    for (int r=0;r<ROWS_F;r++) gi[(size_t)(r0+r)*192 + tid] = acc[r];
  }
}

// numpy-exact pairwise block sum (leaf of the depth-10 perfect tree)
__device__ float np_block_sum(const float* __restrict__ f0s, int off, int n, float kf){
  float r[8];
  #pragma unroll
  for (int j=0;j<8;j++) r[j] = __fmul_rn(f0_up_elem(f0s, off+j), kf);
  int lim = n - (n & 7);
  int i = 8;
  for (; i<lim; i+=8){
    #pragma unroll
    for (int j=0;j<8;j++)
      r[j] = __fadd_rn(r[j], __fmul_rn(f0_up_elem(f0s, off+i+j), kf));
  }
  float res = __fadd_rn(__fadd_rn(__fadd_rn(r[0],r[1]), __fadd_rn(r[2],r[3])),
                        __fadd_rn(__fadd_rn(r[4],r[5]), __fadd_rn(r[6],r[7])));
  for (; i<n; i++)
    res = __fadd_rn(res, __fmul_rn(f0_up_elem(f0s, off+i), kf));
  return res;
}

// ---------------- fused mid: GRU + STFT + meanf0 ----------------
#define MID_GRU   BB
#define MID_MF    (MID_GRU + BB*32)
#define STFT_JOBS (2*BB*NFRAMES)
#define MID_STFT_BLOCKS ((STFT_JOBS+5)/6)
#define MID_BLOCKS (MID_MF + MID_STFT_BLOCKS)

#define RL(x,l) __uint_as_float(__builtin_amdgcn_readlane(__float_as_uint(x), (l)))

#define CH  25
#define NCH 20

__device__ __forceinline__ float fsig(float x){
  return __fdividef(1.0f, 1.0f + __expf(-x));
}
__device__ __forceinline__ float ftanh(float x){
  return fmaf(-2.0f, __fdividef(1.0f, 1.0f + __expf(2.0f*x)), 1.0f);
}

// (1,4): min-1-wave/EU budget (512 VGPR) to force weight residency; max 4
// keeps >=2 waves/SIMD placeable for the 6-wave block.
__global__
__attribute__((amdgpu_flat_work_group_size(384,384)))
__attribute__((amdgpu_waves_per_eu(1,4)))
void k_mid(
    const float* __restrict__ gi, const float* __restrict__ Whh,
    const float* __restrict__ bhh, float* __restrict__ gout,
    const float* __restrict__ f0, const float* __restrict__ nL,
    const float* __restrict__ nR, float* __restrict__ ws){
  __shared__ __align__(16) float sh[13696];
  int blk = blockIdx.x;
  int tid = threadIdx.x;

  if (blk < MID_GRU){
    float* gibuf = sh;            // [2][4800]
    float* hist  = sh + 9600;     // [64][64]
    int b = blk;
    int j = tid & 63;
    v2f wr2[32], wz2[32], wn2[32];
    float br=0.f, bz=0.f, bn=0.f;
    if (tid < 64){
      #pragma unroll
      for (int i=0;i<16;i++){
        float4 a = *(const float4*)(Whh + (size_t)(j)*64     + i*4);
        float4 c = *(const float4*)(Whh + (size_t)(64+j)*64  + i*4);
        float4 d = *(const float4*)(Whh + (size_t)(128+j)*64 + i*4);
        wr2[2*i] = (v2f){a.x, a.y}; wr2[2*i+1] = (v2f){a.z, a.w};
        wz2[2*i] = (v2f){c.x, c.y}; wz2[2*i+1] = (v2f){c.z, c.w};
        wn2[2*i] = (v2f){d.x, d.y}; wn2[2*i+1] = (v2f){d.z, d.w};
      }
      br = bhh[j]; bz = bhh[64+j]; bn = bhh[128+j];
    }
    const float* gbase = gi + (size_t)b*TT*192;
    if (tid >= 64){
      int pt = tid - 64;
      for (int idx = pt; idx < CH*48; idx += 192){
        float4 v = *(const float4*)(gbase + idx*4);
        *(float4*)&gibuf[idx*4] = v;
      }
    }
    __syncthreads();
    float hreg = 0.0f;
    float* op = gout + (size_t)b*TT*64;
    for (int c=0; c<NCH; c++){
      if (tid >= 64){
        if (c+1 < NCH){
          int pt = tid - 64;
          const float* src = gbase + (size_t)(c+1)*CH*192;
          float* dst = &gibuf[((c+1)&1)*4800];
          for (int idx = pt; idx < CH*48; idx += 192){
            float4 v = *(const float4*)(src + idx*4);
            *(float4*)&dst[idx*4] = v;
          }
        }
      } else {
        const float* gch = &gibuf[(c&1)*4800];
        for (int tt=0; tt<CH; tt++){
          int t = c*CH + tt;
          float gr0 = gch[tt*192 + j];
          float gz0 = gch[tt*192 + 64 + j];
          float gn0 = gch[tt*192 + 128 + j];
          v2f AR0={0.f,0.f}, AR1={0.f,0.f};
          v2f AZ0={0.f,0.f}, AZ1={0.f,0.f};
          v2f AN0={0.f,0.f}, AN1={0.f,0.f};
          #pragma unroll
          for (int i=0;i<16;i++){
            v2f hA, hB;
            hA.x = RL(hreg, 2*i);    hA.y = RL(hreg, 2*i+1);
            hB.x = RL(hreg, 32+2*i); hB.y = RL(hreg, 33+2*i);
            AR0 = __builtin_elementwise_fma(wr2[i],    hA, AR0);
            AR1 = __builtin_elementwise_fma(wr2[16+i], hB, AR1);
            AZ0 = __builtin_elementwise_fma(wz2[i],    hA, AZ0);
            AZ1 = __builtin_elementwise_fma(wz2[16+i], hB, AZ1);
            AN0 = __builtin_elementwise_fma(wn2[i],    hA, AN0);
            AN1 = __builtin_elementwise_fma(wn2[16+i], hB, AN1);
          }
          float ar = __fadd_rn(__fadd_rn(AR0.x,AR0.y), __fadd_rn(AR1.x,AR1.y));
          float az = __fadd_rn(__fadd_rn(AZ0.x,AZ0.y), __fadd_rn(AZ1.x,AZ1.y));
          float an = __fadd_rn(__fadd_rn(AN0.x,AN0.y), __fadd_rn(AN1.x,AN1.y));
          float r = fsig(gr0 + ar + br);
          float z = fsig(gz0 + az + bz);
          float n = ftanh(gn0 + r*(an+bn));
          hreg = (1.0f - z)*n + z*hreg;
          int th = t & 63;
          hist[th*64 + j] = hreg;
          if (th == 63 || t == TT-1){
            int base_t = t - th;
            int per = th + 1;
            int nb = per >> 2;
            float* dst2 = op + base_t*64 + j*per;
            for (int q=0;q<nb;q++){
              float4 v = *(float4*)&hist[j*per + q*4];
              *(float4*)&dst2[q*4] = v;
            }
          }
        }
      }
      __syncthreads();
    }
  } else if (blk < MID_MF){
    int bk = blk - MID_GRU;
    int b = bk >> 5, k = bk & 31;
    float kf = (float)(k+1);
    float* f0s = sh;
    float* red = sh + 512;
    for (int i=tid;i<TT;i+=384) f0s[i] = f0[b*TT+i];
    __syncthreads();
    if (tid < 256){
      float lv[4];
      #pragma unroll
      for (int q=0;q<4;q++){
        int leafIdx = tid*4 + q;
        int off = 0, n = NSAMP;
        #pragma unroll
        for (int lvl=9; lvl>=0; --lvl){
          int n2 = (n>>1); n2 -= (n2 & 7);
          if ((leafIdx >> lvl) & 1){ off += n2; n -= n2; } else { n = n2; }
        }
        lv[q] = np_block_sum(f0s, off, n, kf);
      }
      red[tid] = __fadd_rn(__fadd_rn(lv[0],lv[1]), __fadd_rn(lv[2],lv[3]));
    }
    __syncthreads();
    for (int cnt=256; cnt>1; cnt>>=1){
      int half = cnt>>1;
      float v = 0.0f;
      if (tid < half) v = __fadd_rn(red[2*tid], red[2*tid+1]);
      __syncthreads();
      if (tid < half) red[tid] = v;
      __syncthreads();
    }
    if (tid==0){
      float mf = __fdiv_rn(red[0], 120000.0f);
      float c1 = __fmul_rn((float)(2.0*M_PI/48000.0), mf);
      ws[OFF_C1 + b*32 + k] = c1;
    }
  } else {
    int base = (blk - MID_MF)*6;
    int sub = tid >> 6;
    int j = tid & 63;
    float2* tw = (float2*)sh;
    float* frs = sh + 512 + sub*256;
    if (tid < 256){
      double a = (2.0*M_PI/256.0)*(double)tid;
      tw[tid] = make_float2((float)cos(a), (float)sin(a));
    }
    int jid = base + sub;
    bool act = jid < STFT_JOBS;
    int b=0, f=0; const float* x = nL;
    if (act){
      int ch = jid / (BB*NFRAMES);
      int rem = jid - ch*(BB*NFRAMES);
      b = rem / NFRAMES; f = rem - b*NFRAMES;
      x = (ch ? nR : nL) + (size_t)b*NSAMP;
      for (int n=j;n<256;n+=64){
        double a = (2.0*M_PI/256.0)*(double)n;
        int xi = f*NHOPF + n - 128;
        xi = xi < 0 ? -xi : xi;
        xi = xi >= NSAMP ? 2*(NSAMP-1)-xi : xi;
        float wnd = (float)(0.5 - 0.5*cos(a));
        frs[n] = x[xi]*wnd;
      }
    }
    __syncthreads();
    if (act){
      int ch = jid / (BB*NFRAMES);
      float* spec = ws + (ch ? OFF_SPECR : OFF_SPECL) + (size_t)(b*NFRAMES+f)*258;
      float re0=0.f, im0=0.f, re1=0.f, im1=0.f;
      int m0 = 0;
      #pragma unroll 4
      for (int n=0;n<256;n++){
        float fv = frs[n];
        int m1 = (m0 + ((n&3)<<6)) & 255;
        float2 t0 = tw[m0], t1 = tw[m1];
        re0 = fmaf(fv, t0.x, re0); im0 = fmaf(-fv, t0.y, im0);
        re1 = fmaf(fv, t1.x, re1); im1 = fmaf(-fv, t1.y, im1);
        m0 = (m0 + j) & 255;
      }
      float pq = frs[j] + frs[j+64] + frs[j+128] + frs[j+192];
      pq = (j & 1) ? -pq : pq;
      for (int o2=32;o2>0;o2>>=1) pq += __shfl_down(pq, o2, 64);
      spec[2*j]   = re0; spec[2*j+1]   = im0;
      spec[2*(j+64)] = re1; spec[2*(j+64)+1] = im1;
      if (j==0){ spec[256] = pq; spec[257] = 0.0f; }
    }
  }
}

// ---------------- fused post matmul + heads, 8 rows/block ----------------
#define ROWS_P 8
__global__ __launch_bounds__(384) void k_posthead(
  const float* __restrict__ bpo,
  const float* __restrict__ bhL, const float* __restrict__ bhR,
  const float* __restrict__ bam, const float* __restrict__ bnL,
  const float* __restrict__ bnR, float* __restrict__ ws){
  int r0 = blockIdx.x * ROWS_P;
  int tid = threadIdx.x;
  __shared__ float gs[ROWS_P][HID];
  __shared__ float post[ROWS_P][MLPD];
  const float* gout = ws + OFF_GOUT;
  for (int idx = tid; idx < ROWS_P*HID; idx += 384)
    gs[idx>>6][idx&63] = gout[(size_t)(r0 + (idx>>6))*HID + (idx&63)];
  __syncthreads();
  { // post: c=tid&127, group tid>>7 in {0,1,2} handles rows {0-2,3-5,6-7}
    int c = tid & 127, rg = tid >> 7;
    int rs = rg*3, nr = (rg==2)?2:3;
    const float* wt = ws + OFF_WTPO;
    float acc[3];
    for (int q=0;q<nr;q++) acc[q] = bpo[c];
    for (int i=0;i<HID;i++){
      float w = wt[i*128 + c];
      for (int q=0;q<nr;q++) acc[q] = fmaf(gs[rs+q][i], w, acc[q]);
    }
    for (int q=0;q<nr;q++) post[rs+q][c] = fmaxf(acc[q], 0.0f);
  }
  __syncthreads();
  if (tid < 323){ // heads: one col per thread, all 8 rows
    int c = tid;
    const float* wt = ws + OFF_WTH;
    float bb; bool sp = false; float* o; int oc, ow;
    if (c < 32)      { bb=bhL[c];      o=ws+OFF_HARML; oc=c;     ow=32; }
    else if (c < 64) { bb=bhR[c-32];   o=ws+OFF_HARMR; oc=c-32;  ow=32; }
    else if (c == 64){ bb=bam[0];      o=ws+OFF_AMP;   oc=0;     ow=1; sp=true; }
    else if (c < 194){ bb=bnL[c-65];   o=ws+OFF_NMAGL; oc=c-65;  ow=129; }
    else             { bb=bnR[c-194];  o=ws+OFF_NMAGR; oc=c-194; ow=129; }
    float acc[ROWS_P];
    #pragma unroll
    for (int r=0;r<ROWS_P;r++) acc[r] = bb;
    for (int i=0;i<MLPD;i++){
      float w = wt[i*323 + c];
      #pragma unroll
      for (int r=0;r<ROWS_P;r++) acc[r] = fmaf(post[r][i], w, acc[r]);
    }
    #pragma unroll
    for (int r=0;r<ROWS_P;r++){
      float a = acc[r], v;
      if (sp) v = fmaxf(a, 0.0f) + log1pf(expf(-fabsf(a)));
      else    v = 1.0f/(1.0f+expf(-a));
      o[(size_t)(r0+r)*ow + oc] = v;
    }
  }
}

// ---------------- mag filter + irfft + window (IN-PLACE, rotation twiddle) ----
__global__ __launch_bounds__(256) void k_istft(float* __restrict__ ws){
  int fr = blockIdx.x;
  int ch = blockIdx.y;
  int b = fr / NFRAMES, f = fr - b*NFRAMES;
  float* spec = ws + (ch ? OFF_SPECR : OFF_SPECL) + (size_t)fr*258;
  const float* nmag = ws + (ch ? OFF_NMAGR : OFF_NMAGL) + (size_t)b*TT*NBIN;
  int t = threadIdx.x;
  __shared__ float2 mx[NBIN];
  double a = (2.0*M_PI/256.0)*(double)t;
  float cz = (float)cos(a), sz = (float)sin(a);
  if (t < NBIN){
    float pos = ((float)f + 0.5f) * R_MAG - 0.5f;
    pos = fminf(fmaxf(pos, 0.0f), 499.0f);
    int i0 = (int)pos, i1 = min(i0+1, TT-1);
    float w = pos - (float)i0;
    float mg = nmag[i0*NBIN + t]*(1.0f-w) + nmag[i1*NBIN + t]*w;
    mx[t] = make_float2(spec[2*t]*mg, spec[2*t+1]*mg);
  }
  __syncthreads();
  float acc0 = mx[0].x + ((t&1) ? -mx[128].x : mx[128].x);
  float acc = 0.0f;
  float c = cz, s = sz;
  #pragma unroll 4
  for (int k=1;k<128;k++){
    float2 v = mx[k];
    acc = fmaf(v.x, c, acc);
    acc = fmaf(-v.y, s, acc);
    float ts_ = s*sz, tc_ = c*sz;
    float cn = fmaf(c, cz, -ts_);
    float sn = fmaf(s, cz,  tc_);
    c = cn; s = sn;
  }
  float y = (acc0 + 2.0f*acc) * (1.0f/256.0f);
  float win = 0.5f - 0.5f*cz;
  spec[t] = y*win;
}

// ---------------- final: harmonic synth + OLA gather ----------------
__global__ __launch_bounds__(256) void k_out(const float* __restrict__ f0,
    const float* __restrict__ ws, float* __restrict__ out){
  __shared__ float win2[256];
  __shared__ float c1s[BB*32];
  {
    int t = threadIdx.x;
    double a = (2.0*M_PI/256.0)*(double)t;
    float w = (float)(0.5 - 0.5*cos(a));
    win2[t] = w*w;
    if (t < BB*32) c1s[t] = ws[OFF_C1 + t];
  }
  __syncthreads();
  int idx = blockIdx.x*256 + threadIdx.x;
  if (idx >= BB*2*NSAMP) return;
  int m = idx % NSAMP;
  int bc = idx / NSAMP;
  int ch = bc & 1, b = bc >> 1;
  int i0,i1; float w,w1;
  up_coords(m,&i0,&i1,&w,&w1);
  const float* f0b = f0 + b*TT;
  float f0u = __fadd_rn(__fmul_rn(f0b[i0], w1), __fmul_rn(f0b[i1], w));
  const float* am = ws + OFF_AMP + b*TT;
  float oa = __fadd_rn(__fmul_rn(am[i0], w1), __fmul_rn(am[i1], w));
  const float* ha = ws + (ch ? OFF_HARMR : OFF_HARML) + (size_t)b*TT*NHARM;
  float tm = (float)m;
  float hsum = 0.0f;
  for (int k=1;k<=NHARM;k++){
    float instf = __fmul_rn(f0u, (float)k);
    if (instf < 21600.0f){
      float a0 = ha[i0*NHARM + (k-1)], a1 = ha[i1*NHARM + (k-1)];
      float ak = __fadd_rn(__fmul_rn(a0, w1), __fmul_rn(a1, w));
      float ph = __fmul_rn(c1s[b*32 + (k-1)], tm);
      double rev = (double)ph * 0.15915494309189535;
      double fr2 = rev - floor(rev);
      float rad = (float)((fr2 - (fr2 >= 0.5 ? 1.0 : 0.0)) * 6.283185307179586);
      float s = sinf(rad);
      hsum = __fadd_rn(hsum, __fmul_rn(ak, s));
    }
  }
  float harm = __fmul_rn(hsum, oa);
  int p = m + 128;
  int fhi = min(p >> 6, NFRAMES-1);
  int flo = max((p - 192) >> 6, 0);
  const float* frb = ws + (ch ? OFF_SPECR : OFF_SPECL) + (size_t)b*NFRAMES*258;
  float nacc = 0.0f, wsum = 0.0f;
  for (int f=flo; f<=fhi; f++){
    int n = p - f*NHOPF;
    nacc += frb[f*258 + n];
    wsum += win2[n];
  }
  float noise = nacc / fmaxf(wsum, 1e-11f);
  out[idx] = __fadd_rn(harm, noise);
}

extern "C" void kernel_launch(void* const* d_in, const int* in_sizes, int n_in,
                              void* d_out, int out_size, void* d_ws, size_t ws_size,
                              hipStream_t stream){
  const float* f0  = (const float*)d_in[0];
  const float* ldb = (const float*)d_in[1];
  const float* vel = (const float*)d_in[2];
  const float* nL  = (const float*)d_in[3];
  const float* nR  = (const float*)d_in[4];
  const float* Wp1 = (const float*)d_in[5];
  const float* bp1 = (const float*)d_in[6];
  const float* Wp2 = (const float*)d_in[7];
  const float* bp2 = (const float*)d_in[8];
  const float* Wih = (const float*)d_in[9];
  const float* Whh = (const float*)d_in[10];
  const float* bih = (const float*)d_in[11];
  const float* bhh = (const float*)d_in[12];
  const float* Wpo = (const float*)d_in[13];
  const float* bpo = (const float*)d_in[14];
  const float* WhL = (const float*)d_in[15];
  const float* bhL = (const float*)d_in[16];
  const float* WhR = (const float*)d_in[17];
  const float* bhR = (const float*)d_in[18];
  const float* Wam = (const float*)d_in[19];
  const float* bam = (const float*)d_in[20];
  const float* WnL = (const float*)d_in[21];
  const float* bnL = (const float*)d_in[22];
  const float* WnR = (const float*)d_in[23];
  const float* bnR = (const float*)d_in[24];
  float* ws = (float*)d_ws;
  float* out = (float*)d_out;

  k_prep<<<(PREP_TOT+255)/256, 256, 0, stream>>>(Wp1, Wp2, Wih, Wpo, WhL, WhR, Wam, WnL, WnR, ws);
  k_front<<<BB*TT/ROWS_F, 256, 0, stream>>>(f0, ldb, vel, bp1, bp2, bih, ws);
  k_mid<<<MID_BLOCKS, 384, 0, stream>>>(ws+OFF_GI, Whh, bhh, ws+OFF_GOUT, f0, nL, nR, ws);
  k_posthead<<<BB*TT/ROWS_P, 384, 0, stream>>>(bpo, bhL, bhR, bam, bnL, bnR, ws);
  dim3 gs(BB*NFRAMES, 2);
  k_istft<<<gs, 256, 0, stream>>>(ws);
  k_out<<<(BB*2*NSAMP+255)/256, 256, 0, stream>>>(f0, ws, out);
}